// Round 7
// baseline (4080.025 us; speedup 1.0000x reference)
//
#include <hip/hip_runtime.h>

// GCRN (AGCRN-style) on gfx950. Inputs/outputs fp32; internal compute bf16 MFMA.
// A = softmax(relu(E E^T)); AA = [A; 2A^2] stacked (T2 = 2A^2 - I folded into
// weights: W0' = W0 - W2).
// Fused cells, two dispatches per cell. Round 7: BARRIER-FREE K-loops —
// MFMA fragments map 1:1 to global rows, so A/B operands are loaded per-lane
// (bf16x8 = global_load_dwordx4) straight from L2; no LDS staging, no
// __syncthreads in any K-loop. Only the Sh C-layout -> A-layout transform
// round-trips through LDS (1 barrier per kernel). Grid is 512 = 2 blocks/CU
// (grid-capped occupancy), so VGPRs are free up to 256.

typedef __attribute__((ext_vector_type(8))) short bf16x8;
typedef __attribute__((ext_vector_type(4))) float f32x4;
typedef __attribute__((ext_vector_type(4))) unsigned short u16x4;

__device__ __forceinline__ float b2f(unsigned short u) {
    union { unsigned int i; float f; } v; v.i = ((unsigned int)u) << 16; return v.f;
}
__device__ __forceinline__ unsigned short f2b(float f) {
    union { float f; unsigned int i; } v; v.f = f;
    unsigned int r = v.i + 0x7FFFu + ((v.i >> 16) & 1u);
    return (unsigned short)(r >> 16);
}

// LDS dest is wave-uniform base + lane*16 (m104/m108 rule) — used only in the
// small preamble GEMM.
#define GLOAD_LDS16(g, l) __builtin_amdgcn_global_load_lds( \
    (const __attribute__((address_space(1))) void*)(g),     \
    (__attribute__((address_space(3))) void*)(l), 16, 0, 0)

// ---------------------------------------------------------------------------
// Generic bf16 GEMM (preamble only): C[m,n] = scale * sum_k P[m,k]*QT[n,k].
// ---------------------------------------------------------------------------
__global__ __launch_bounds__(256) void gemm_bt(
    const unsigned short* __restrict__ P, int lda,
    const unsigned short* __restrict__ QT, int ldb,
    unsigned short* __restrict__ C, int ldc,
    int K, float scale)
{
    __shared__ __align__(16) unsigned short As[128 * 32];
    __shared__ __align__(16) unsigned short Bs[128 * 32];
    const int tid = threadIdx.x;
    const int m0 = blockIdx.y << 7, n0 = blockIdx.x << 7;
    const int w = tid >> 6, l = tid & 63;
    const int wm = (w >> 1) << 6, wn = (w & 1) << 6;
    const int lr = l & 15, lq = l >> 4;
    const int arow = tid >> 2, ak = (tid & 3) << 3;
    f32x4 acc[4][4] = {};

    for (int k0 = 0; k0 < K; k0 += 32) {
#pragma unroll
        for (int p = 0; p < 2; ++p)
            GLOAD_LDS16(P + (size_t)(m0 + arow + (p << 6)) * lda + k0 + ak,
                        &As[((arow + (p << 6)) << 5) + ak]);
#pragma unroll
        for (int p = 0; p < 2; ++p)
            GLOAD_LDS16(QT + (size_t)(n0 + arow + (p << 6)) * ldb + k0 + ak,
                        &Bs[((arow + (p << 6)) << 5) + ak]);
        __syncthreads();
        bf16x8 a[4], b[4];
#pragma unroll
        for (int i = 0; i < 4; ++i)
            a[i] = *(const bf16x8*)&As[((wm + (i << 4) + lr) << 5) + (lq << 3)];
#pragma unroll
        for (int j = 0; j < 4; ++j)
            b[j] = *(const bf16x8*)&Bs[((wn + (j << 4) + lr) << 5) + (lq << 3)];
#pragma unroll
        for (int i = 0; i < 4; ++i)
#pragma unroll
            for (int j = 0; j < 4; ++j)
                acc[i][j] = __builtin_amdgcn_mfma_f32_16x16x32_bf16(a[i], b[j], acc[i][j], 0, 0, 0);
        __syncthreads();
    }
#pragma unroll
    for (int i = 0; i < 4; ++i)
#pragma unroll
        for (int j = 0; j < 4; ++j)
#pragma unroll
            for (int r = 0; r < 4; ++r) {
                const int m = m0 + wm + (i << 4) + (lq << 2) + r;
                const int n = n0 + wn + (j << 4) + lr;
                C[(size_t)m * ldc + n] = f2b(acc[i][j][r] * scale);
            }
}

// ---------------------------------------------------------------------------
// cell_gate: grid 512 = (b in [0,64)) x (n0-tile in [0,8)), 256 threads.
// ---------------------------------------------------------------------------
__global__ __launch_bounds__(256) void cell_gate(
    const unsigned short* __restrict__ AA, const unsigned short* __restrict__ XhT,
    const unsigned short* __restrict__ Hb, const unsigned short* __restrict__ WT,
    const float* __restrict__ bias, const float* __restrict__ wx,
    const float* __restrict__ xin, int t,
    const unsigned short* __restrict__ XSgT, int xsrow,
    const unsigned short* __restrict__ Go,
    const float* __restrict__ prW, const float* __restrict__ prb,
    float* __restrict__ Sgo,
    unsigned short* __restrict__ Zb, unsigned short* __restrict__ ZhT,
    float* __restrict__ R, int dec, int goflag)
{
    __shared__ __align__(16) unsigned short Shs[256 * 72];  // 36 KB
    __shared__ float SgoS[256];
    const int tid = threadIdx.x;
    const int b = blockIdx.x >> 3, n0 = (blockIdx.x & 7) << 7;
    const int w = tid >> 6, l = tid & 63;
    const int lr = l & 15, lq = l >> 4;

    // ---- Phase 1: Sh[256][64] = AA[rows] @ XhT[b-rows]^T, barrier-free ----
    {
        const int wmP = w << 6;                           // wave's M base 0..192
        const int rowoff = (w >= 2) ? (896 + n0) : n0;    // AA global row base
        f32x4 acc[4][4] = {};
        for (int k0 = 0; k0 < 1024; k0 += 32) {
            bf16x8 a[4], bb[4];
#pragma unroll
            for (int i = 0; i < 4; ++i)
                a[i] = *(const bf16x8*)(AA + (size_t)(rowoff + wmP + (i << 4) + lr) * 1024 + k0 + (lq << 3));
#pragma unroll
            for (int j = 0; j < 4; ++j)
                bb[j] = *(const bf16x8*)(XhT + (size_t)((b << 6) + (j << 4) + lr) * 1024 + k0 + (lq << 3));
#pragma unroll
            for (int i = 0; i < 4; ++i)
#pragma unroll
                for (int j = 0; j < 4; ++j)
                    acc[i][j] = __builtin_amdgcn_mfma_f32_16x16x32_bf16(a[i], bb[j], acc[i][j], 0, 0, 0);
        }
        // Sh -> LDS (bf16), C-layout -> row-major
#pragma unroll
        for (int i = 0; i < 4; ++i)
#pragma unroll
            for (int j = 0; j < 4; ++j)
#pragma unroll
                for (int r = 0; r < 4; ++r) {
                    const int m = wmP + (i << 4) + (lq << 2) + r;
                    const int c = (j << 4) + lr;
                    Shs[m * 72 + c] = f2b(acc[i][j][r]);
                }
        if (dec) {
            float pw[4];
#pragma unroll
            for (int j = 0; j < 4; ++j) pw[j] = prW[(j << 4) + lr];
            const float pb0 = prb[0];
#pragma unroll
            for (int i = 0; i < 4; ++i)
#pragma unroll
                for (int r = 0; r < 4; ++r) {
                    float v = acc[i][0][r] * pw[0] + acc[i][1][r] * pw[1]
                            + acc[i][2][r] * pw[2] + acc[i][3][r] * pw[3];
                    v += __shfl_down(v, 8, 16);
                    v += __shfl_down(v, 4, 16);
                    v += __shfl_down(v, 2, 16);
                    v += __shfl_down(v, 1, 16);
                    if (lr == 0) {
                        const int m = wmP + (i << 4) + (lq << 2) + r;
                        const int grow = (m < 128) ? (n0 + m) : (896 + n0 + m);
                        // t=0: GO token is zero -> A@go = 0 (goflag==0)
                        const float val = goflag
                            ? (v + pb0 * ((m < 128) ? 1.f : 2.f)) : 0.f;
                        Sgo[(size_t)grow * 64 + b] = val;
                        SgoS[m] = val;
                    }
                }
        }
    }
    __syncthreads();   // the only barrier: Shs/SgoS ready for all waves

    // ---- Phase 2: zr = sigmoid([h | Sh0 | Sh1] @ W + bias + corr) ----
    const int wm2 = (w >> 1) << 6, wn2 = (w & 1) << 6;
    f32x4 acc2[4][4] = {};
    for (int kk0 = 0; kk0 < 192; kk0 += 32) {
        bf16x8 a[4], bb[4];
        if (kk0 < 64) {
#pragma unroll
            for (int i = 0; i < 4; ++i)
                a[i] = *(const bf16x8*)(Hb + ((size_t)(b << 10) + n0 + wm2 + (i << 4) + lr) * 64 + kk0 + (lq << 3));
        } else {
            const int rowb = (kk0 >= 128) ? 128 : 0;
            const int c0 = kk0 & 63;
#pragma unroll
            for (int i = 0; i < 4; ++i)
                a[i] = *(const bf16x8*)&Shs[(rowb + wm2 + (i << 4) + lr) * 72 + c0 + (lq << 3)];
        }
#pragma unroll
        for (int j = 0; j < 4; ++j)
            bb[j] = *(const bf16x8*)(WT + (size_t)(wn2 + (j << 4) + lr) * 192 + kk0 + (lq << 3));
#pragma unroll
        for (int i = 0; i < 4; ++i)
#pragma unroll
            for (int j = 0; j < 4; ++j)
                acc2[i][j] = __builtin_amdgcn_mfma_f32_16x16x32_bf16(a[i], bb[j], acc2[i][j], 0, 0, 0);
    }

#pragma unroll
    for (int i = 0; i < 4; ++i) {
        const int nb_loc = wm2 + (i << 4) + (lq << 2);      // local node 0..127
        const int node_base = n0 + nb_loc;
        float c0[4], c1[4], c2[4], c3[4], c4[4], c5[4];
        for (int r = 0; r < 4; ++r) {
            const int node = node_base + r;
            if (!dec) {
                c0[r] = xin[((b * 12 + t) << 10) + node];
                c1[r] = b2f(XSgT[(size_t)(xsrow + t * 64 + b) * 2048 + node]);
                c2[r] = b2f(XSgT[(size_t)(xsrow + t * 64 + b) * 2048 + 1024 + node]);
                c3[r] = c4[r] = c5[r] = 0.f;
            } else {
                c0[r] = b2f(Go[(b << 10) + node]);
                c1[r] = xin[((b * 12 + t) << 10) + node];
                c2[r] = SgoS[nb_loc + r];
                c3[r] = b2f(XSgT[(size_t)(xsrow + t * 64 + b) * 2048 + node]);
                c4[r] = SgoS[128 + nb_loc + r];
                c5[r] = b2f(XSgT[(size_t)(xsrow + t * 64 + b) * 2048 + 1024 + node]);
            }
        }
#pragma unroll
        for (int j = 0; j < 4; ++j) {
            const int jc = wn2 + (j << 4) + lr;
            const float bj = bias[jc];
            const float w0 = wx[jc], w1 = wx[128 + jc], w2 = wx[256 + jc];
            float w3 = 0.f, w4 = 0.f, w5 = 0.f;
            if (dec) { w3 = wx[384 + jc]; w4 = wx[512 + jc]; w5 = wx[640 + jc]; }
            if (jc < 64) {
                u16x4 pack;
                for (int r = 0; r < 4; ++r) {
                    float v = acc2[i][j][r] + bj + c0[r] * w0 + c1[r] * w1 + c2[r] * w2
                              + c3[r] * w3 + c4[r] * w4 + c5[r] * w5;
                    float g = 1.f / (1.f + __expf(-v));
                    const int node = node_base + r;
                    const size_t idx = ((size_t)(b << 10) + node) * 64 + jc;
                    float zh = g * b2f(Hb[idx]);   // bf16 h; zh is re-rounded anyway
                    unsigned short zb = f2b(zh);
                    Zb[idx] = zb;
                    pack[r] = zb;
                }
                *(u16x4*)&ZhT[(size_t)((b << 6) + jc) * 1024 + node_base] = pack;
            } else {
                for (int r = 0; r < 4; ++r) {
                    float v = acc2[i][j][r] + bj + c0[r] * w0 + c1[r] * w1 + c2[r] * w2
                              + c3[r] * w3 + c4[r] * w4 + c5[r] * w5;
                    float g = 1.f / (1.f + __expf(-v));
                    const int node = node_base + r;
                    R[((size_t)(b << 10) + node) * 64 + (jc - 64)] = g;
                }
            }
        }
    }
}

// ---------------------------------------------------------------------------
// cell_update: grid 512 = (b, n0-tile), 256 threads.
// ---------------------------------------------------------------------------
__global__ __launch_bounds__(256) void cell_update(
    const unsigned short* __restrict__ AA, const unsigned short* __restrict__ ZhT,
    const unsigned short* __restrict__ Zb, const unsigned short* __restrict__ WT,
    const float* __restrict__ bias, const float* __restrict__ wx,
    const float* __restrict__ xin, int t,
    const unsigned short* __restrict__ XSgT, int xsrow,
    const float* __restrict__ Sgo, const float* __restrict__ Rg,
    float* __restrict__ H32, unsigned short* __restrict__ Hb,
    unsigned short* __restrict__ XhT,
    const float* __restrict__ prW, const float* __restrict__ prb,
    unsigned short* __restrict__ Go, float* __restrict__ outp, int dec)
{
    __shared__ __align__(16) unsigned short Shs[256 * 72];  // 36 KB
    const int tid = threadIdx.x;
    const int b = blockIdx.x >> 3, n0 = (blockIdx.x & 7) << 7;
    const int w = tid >> 6, l = tid & 63;
    const int lr = l & 15, lq = l >> 4;

    // ---- Phase 1: Sz[256][64] = AA @ ZhT[b-rows]^T, barrier-free ----
    {
        const int wmP = w << 6;
        const int rowoff = (w >= 2) ? (896 + n0) : n0;
        f32x4 acc[4][4] = {};
        for (int k0 = 0; k0 < 1024; k0 += 32) {
            bf16x8 a[4], bb[4];
#pragma unroll
            for (int i = 0; i < 4; ++i)
                a[i] = *(const bf16x8*)(AA + (size_t)(rowoff + wmP + (i << 4) + lr) * 1024 + k0 + (lq << 3));
#pragma unroll
            for (int j = 0; j < 4; ++j)
                bb[j] = *(const bf16x8*)(ZhT + (size_t)((b << 6) + (j << 4) + lr) * 1024 + k0 + (lq << 3));
#pragma unroll
            for (int i = 0; i < 4; ++i)
#pragma unroll
                for (int j = 0; j < 4; ++j)
                    acc[i][j] = __builtin_amdgcn_mfma_f32_16x16x32_bf16(a[i], bb[j], acc[i][j], 0, 0, 0);
        }
#pragma unroll
        for (int i = 0; i < 4; ++i)
#pragma unroll
            for (int j = 0; j < 4; ++j)
#pragma unroll
                for (int r = 0; r < 4; ++r) {
                    const int m = wmP + (i << 4) + (lq << 2) + r;
                    const int c = (j << 4) + lr;
                    Shs[m * 72 + c] = f2b(acc[i][j][r]);
                }
    }
    __syncthreads();   // the only barrier

    // ---- Phase 2: hc = tanh([zh | Sz0 | Sz1] @ Wu + bias + corr) ----
    const int wm2 = w << 5;
    f32x4 acc2[2][4] = {};
    for (int kk0 = 0; kk0 < 192; kk0 += 32) {
        bf16x8 a[2], bb[4];
        if (kk0 < 64) {
#pragma unroll
            for (int i = 0; i < 2; ++i)
                a[i] = *(const bf16x8*)(Zb + ((size_t)(b << 10) + n0 + wm2 + (i << 4) + lr) * 64 + kk0 + (lq << 3));
        } else {
            const int rowb = (kk0 >= 128) ? 128 : 0;
            const int c0 = kk0 & 63;
#pragma unroll
            for (int i = 0; i < 2; ++i)
                a[i] = *(const bf16x8*)&Shs[(rowb + wm2 + (i << 4) + lr) * 72 + c0 + (lq << 3)];
        }
#pragma unroll
        for (int j = 0; j < 4; ++j)
            bb[j] = *(const bf16x8*)(WT + (size_t)((j << 4) + lr) * 192 + kk0 + (lq << 3));
#pragma unroll
        for (int i = 0; i < 2; ++i)
#pragma unroll
            for (int j = 0; j < 4; ++j)
                acc2[i][j] = __builtin_amdgcn_mfma_f32_16x16x32_bf16(a[i], bb[j], acc2[i][j], 0, 0, 0);
    }

    float pw[4];
    if (dec) {
#pragma unroll
        for (int j = 0; j < 4; ++j) pw[j] = prW[(j << 4) + lr];
    }

#pragma unroll
    for (int i = 0; i < 2; ++i) {
        const int node_base = n0 + wm2 + (i << 4) + (lq << 2);
        float c0[4], c1[4], c2[4], c3[4], c4[4], c5[4];
        for (int r = 0; r < 4; ++r) {
            const int node = node_base + r;
            if (!dec) {
                c0[r] = xin[((b * 12 + t) << 10) + node];
                c1[r] = b2f(XSgT[(size_t)(xsrow + t * 64 + b) * 2048 + node]);
                c2[r] = b2f(XSgT[(size_t)(xsrow + t * 64 + b) * 2048 + 1024 + node]);
                c3[r] = c4[r] = c5[r] = 0.f;
            } else {
                c0[r] = b2f(Go[(b << 10) + node]);
                c1[r] = xin[((b * 12 + t) << 10) + node];
                c2[r] = Sgo[(size_t)node * 64 + b];
                c3[r] = b2f(XSgT[(size_t)(xsrow + t * 64 + b) * 2048 + node]);
                c4[r] = Sgo[(size_t)(1024 + node) * 64 + b];
                c5[r] = b2f(XSgT[(size_t)(xsrow + t * 64 + b) * 2048 + 1024 + node]);
            }
        }
        float psum[4] = {0.f, 0.f, 0.f, 0.f};
#pragma unroll
        for (int j = 0; j < 4; ++j) {
            const int jc = (j << 4) + lr;
            const float bj = bias[jc];
            const float w0 = wx[jc], w1 = wx[64 + jc], w2 = wx[128 + jc];
            float w3 = 0.f, w4 = 0.f, w5 = 0.f;
            if (dec) { w3 = wx[192 + jc]; w4 = wx[256 + jc]; w5 = wx[320 + jc]; }
            u16x4 pack;
            for (int r = 0; r < 4; ++r) {
                float v = acc2[i][j][r] + bj + c0[r] * w0 + c1[r] * w1 + c2[r] * w2
                          + c3[r] * w3 + c4[r] * w4 + c5[r] * w5;
                float hc = tanhf(v);
                const int node = node_base + r;
                const size_t idx = ((size_t)(b << 10) + node) * 64 + jc;
                float rr = Rg[idx];
                float hn = rr * H32[idx] + (1.f - rr) * hc;
                H32[idx] = hn;
                unsigned short hb = f2b(hn);
                Hb[idx] = hb;
                pack[r] = hb;
                if (dec) psum[r] += hn * pw[j];
            }
            *(u16x4*)&XhT[(size_t)((b << 6) + jc) * 1024 + node_base] = pack;
        }
        if (dec) {
#pragma unroll
            for (int r = 0; r < 4; ++r) {
                float v = psum[r];
                v += __shfl_down(v, 8, 16);
                v += __shfl_down(v, 4, 16);
                v += __shfl_down(v, 2, 16);
                v += __shfl_down(v, 1, 16);
                if (lr == 0) {
                    const int node = node_base + r;
                    const float go = v + prb[0];
                    Go[(b << 10) + node] = f2b(go);
                    outp[((size_t)(b * 12 + t) << 10) + node] = go;
                }
            }
        }
    }
}

// ---------------------------------------------------------------------------
__global__ __launch_bounds__(256) void adj_softmax(
    const float* __restrict__ E, unsigned short* __restrict__ A)
{
    __shared__ float Es[8192];
    __shared__ float vals[1024];
    __shared__ float red[8];
    const int tid = threadIdx.x;
    const int r = blockIdx.x;
    for (int i = tid; i < 8192; i += 256) Es[i] = E[i];
    __syncthreads();
    float er[8];
#pragma unroll
    for (int e = 0; e < 8; ++e) er[e] = Es[(r << 3) + e];
    float lmax = -1e30f;
    for (int c = tid; c < 1024; c += 256) {
        float s = 0.f;
#pragma unroll
        for (int e = 0; e < 8; ++e) s += er[e] * Es[(c << 3) + e];
        s = fmaxf(s, 0.f);
        vals[c] = s;
        lmax = fmaxf(lmax, s);
    }
    for (int off = 32; off; off >>= 1) lmax = fmaxf(lmax, __shfl_down(lmax, off, 64));
    if ((tid & 63) == 0) red[tid >> 6] = lmax;
    __syncthreads();
    const float m = fmaxf(fmaxf(red[0], red[1]), fmaxf(red[2], red[3]));
    float lsum = 0.f;
    for (int c = tid; c < 1024; c += 256) {
        float e = __expf(vals[c] - m);
        vals[c] = e;
        lsum += e;
    }
    for (int off = 32; off; off >>= 1) lsum += __shfl_down(lsum, off, 64);
    if ((tid & 63) == 0) red[4 + (tid >> 6)] = lsum;
    __syncthreads();
    const float inv = 1.f / (red[4] + red[5] + red[6] + red[7]);
    for (int c = tid; c < 1024; c += 256)
        A[(r << 10) + c] = f2b(vals[c] * inv);
}

__global__ __launch_bounds__(256) void transpose_bf16(
    const unsigned short* __restrict__ src, unsigned short* __restrict__ dst)
{
    __shared__ unsigned short tile[64][65];
    const int bx = blockIdx.x & 15, by = blockIdx.x >> 4;
    const int x0 = bx << 6, y0 = by << 6;
    for (int i = threadIdx.x; i < 4096; i += 256) {
        const int r = i >> 6, c = i & 63;
        tile[r][c] = src[((y0 + r) << 10) + x0 + c];
    }
    __syncthreads();
    for (int i = threadIdx.x; i < 4096; i += 256) {
        const int r = i >> 6, c = i & 63;
        dst[((x0 + r) << 10) + y0 + c] = tile[c][r];
    }
}

__global__ __launch_bounds__(256) void build_xall(
    const float* __restrict__ x, const float* __restrict__ y,
    unsigned short* __restrict__ XallT)
{
    const int id = blockIdx.x * 256 + threadIdx.x;
    const int row = id >> 10, n = id & 1023;
    int t, b;
    const float* src;
    if (row < 768) { t = row >> 6; b = row & 63; src = x; }
    else { const int rr = row - 768; t = rr >> 6; b = rr & 63; src = y; }
    XallT[id] = f2b(src[((b * 12 + t) << 10) + n]);
}

__global__ __launch_bounds__(256) void wprep(
    const float* egW, const float* egb,
    const float* euW, const float* eub,
    const float* dgW, const float* dgb,
    const float* duW, const float* dub,
    const float* pW, const float* pb,
    unsigned short* WgTe, unsigned short* WuTe, unsigned short* WgTd, unsigned short* WuTd,
    float* wxge, float* wxue, float* wxgd, float* wxud,
    float* bge, float* bue, float* bgd, float* bud,
    float* projW, float* projb)
{
    const int tid0 = blockIdx.x * 256 + threadIdx.x;
    const int stride = 256 * gridDim.x;
    for (int i = tid0; i < 128 * 192; i += stride) {
        const int j = i / 192, kk = i % 192, k = kk >> 6, c = kk & 63;
        float v = egW[(k * 65 + 1 + c) * 128 + j];
        if (k == 0) v -= egW[(131 + c) * 128 + j];
        WgTe[i] = f2b(v);
    }
    for (int i = tid0; i < 64 * 192; i += stride) {
        const int j = i / 192, kk = i % 192, k = kk >> 6, c = kk & 63;
        float v = euW[(k * 65 + 1 + c) * 64 + j];
        if (k == 0) v -= euW[(131 + c) * 64 + j];
        WuTe[i] = f2b(v);
    }
    for (int i = tid0; i < 128 * 192; i += stride) {
        const int j = i / 192, kk = i % 192, k = kk >> 6, c = kk & 63;
        float v = dgW[(k * 66 + 2 + c) * 128 + j];
        if (k == 0) v -= dgW[(134 + c) * 128 + j];
        WgTd[i] = f2b(v);
    }
    for (int i = tid0; i < 64 * 192; i += stride) {
        const int j = i / 192, kk = i % 192, k = kk >> 6, c = kk & 63;
        float v = duW[(k * 66 + 2 + c) * 64 + j];
        if (k == 0) v -= duW[(134 + c) * 64 + j];
        WuTd[i] = f2b(v);
    }
    for (int i = tid0; i < 384; i += stride) {
        const int k = i >> 7, j = i & 127;
        float v;
        if (k == 0) v = egW[j] - egW[130 * 128 + j];
        else if (k == 1) v = egW[65 * 128 + j];
        else v = egW[130 * 128 + j];
        wxge[i] = v;
    }
    for (int i = tid0; i < 192; i += stride) {
        const int k = i >> 6, j = i & 63;
        float v;
        if (k == 0) v = euW[j] - euW[130 * 64 + j];
        else if (k == 1) v = euW[65 * 64 + j];
        else v = euW[130 * 64 + j];
        wxue[i] = v;
    }
    for (int i = tid0; i < 768; i += stride) {
        const int k = i >> 7, j = i & 127;
        float v;
        switch (k) {
            case 0: v = dgW[j] - dgW[132 * 128 + j]; break;
            case 1: v = dgW[128 + j] - dgW[133 * 128 + j]; break;
            case 2: v = dgW[66 * 128 + j]; break;
            case 3: v = dgW[67 * 128 + j]; break;
            case 4: v = dgW[132 * 128 + j]; break;
            default: v = dgW[133 * 128 + j]; break;
        }
        wxgd[i] = v;
    }
    for (int i = tid0; i < 384; i += stride) {
        const int k = i >> 6, j = i & 63;
        float v;
        switch (k) {
            case 0: v = duW[j] - duW[132 * 64 + j]; break;
            case 1: v = duW[64 + j] - duW[133 * 64 + j]; break;
            case 2: v = duW[66 * 64 + j]; break;
            case 3: v = duW[67 * 64 + j]; break;
            case 4: v = duW[132 * 64 + j]; break;
            default: v = duW[133 * 64 + j]; break;
        }
        wxud[i] = v;
    }
    for (int i = tid0; i < 128; i += stride) bge[i] = egb[i];
    for (int i = tid0; i < 64; i += stride) bue[i] = eub[i];
    for (int i = tid0; i < 128; i += stride) bgd[i] = dgb[i];
    for (int i = tid0; i < 64; i += stride) bud[i] = dub[i];
    for (int i = tid0; i < 64; i += stride) projW[i] = pW[i];
    if (tid0 == 0) projb[0] = pb[0];
}

// ---------------------------------------------------------------------------
extern "C" void kernel_launch(void* const* d_in, const int* in_sizes, int n_in,
                              void* d_out, int out_size, void* d_ws, size_t ws_size,
                              hipStream_t stream)
{
    (void)in_sizes; (void)n_in; (void)out_size; (void)ws_size;
    const float* x    = (const float*)d_in[0];
    const float* ycov = (const float*)d_in[1];
    const float* E    = (const float*)d_in[2];
    const float* egW  = (const float*)d_in[3];
    const float* egb  = (const float*)d_in[4];
    const float* euW  = (const float*)d_in[5];
    const float* eub  = (const float*)d_in[6];
    const float* dgW  = (const float*)d_in[7];
    const float* dgb  = (const float*)d_in[8];
    const float* duW  = (const float*)d_in[9];
    const float* dub  = (const float*)d_in[10];
    const float* pW   = (const float*)d_in[11];
    const float* pb   = (const float*)d_in[12];
    float* out = (float*)d_out;

    size_t off = 0;
    auto carve = [&](size_t bytes) -> void* {
        void* p = (char*)d_ws + off;
        off += (bytes + 255) & ~(size_t)255;
        return p;
    };
    unsigned short* AA    = (unsigned short*)carve(2048ull * 1024 * 2); // [A; 2A^2]
    unsigned short* XSgT  = (unsigned short*)carve(1536ull * 2048 * 2);
    unsigned short* XhT   = (unsigned short*)carve(4096ull * 1024 * 2);
    unsigned short* ZhT   = (unsigned short*)carve(4096ull * 1024 * 2);
    unsigned short* Hb    = (unsigned short*)carve(65536ull * 64 * 2);
    float*          H32   = (float*)carve(65536ull * 64 * 4);
    unsigned short* Zb    = (unsigned short*)carve(65536ull * 64 * 2);
    float*          R     = (float*)carve(65536ull * 64 * 4);
    float*          Sgo   = (float*)carve(2048ull * 64 * 4);
    unsigned short* Go    = (unsigned short*)carve(65536ull * 2);
    unsigned short* WgTe  = (unsigned short*)carve(128ull * 192 * 2);
    unsigned short* WuTe  = (unsigned short*)carve(64ull * 192 * 2);
    unsigned short* WgTd  = (unsigned short*)carve(128ull * 192 * 2);
    unsigned short* WuTd  = (unsigned short*)carve(64ull * 192 * 2);
    float* wxge = (float*)carve(384 * 4);
    float* wxue = (float*)carve(192 * 4);
    float* wxgd = (float*)carve(768 * 4);
    float* wxud = (float*)carve(384 * 4);
    float* bge  = (float*)carve(128 * 4);
    float* bue  = (float*)carve(64 * 4);
    float* bgd  = (float*)carve(128 * 4);
    float* bud  = (float*)carve(64 * 4);
    float* prW  = (float*)carve(64 * 4);
    float* prb  = (float*)carve(4);
    // Aliases: AT and XallT live inside Zb (both consumed before Zb's first write).
    unsigned short* AT    = Zb;
    unsigned short* XallT = Zb + 1024ull * 1024;

    hipMemsetAsync(XhT, 0, 4096ull * 1024 * 2, stream);
    hipMemsetAsync(Hb, 0, 65536ull * 64 * 2, stream);
    hipMemsetAsync(H32, 0, 65536ull * 64 * 4, stream);
    hipMemsetAsync(Go, 0, 65536ull * 2, stream);

    adj_softmax<<<1024, 256, 0, stream>>>(E, AA);
    transpose_bf16<<<256, 256, 0, stream>>>(AA, AT);
    gemm_bt<<<dim3(8, 8), 256, 0, stream>>>(AA, 1024, AT, 1024, AA + 1024 * 1024, 1024, 1024, 2.0f);
    build_xall<<<6144, 256, 0, stream>>>(x, ycov, XallT);
    gemm_bt<<<dim3(16, 12), 256, 0, stream>>>(XallT, 1024, AA, 1024, XSgT, 2048, 1024, 1.0f);
    wprep<<<64, 256, 0, stream>>>(egW, egb, euW, eub, dgW, dgb, duW, dub, pW, pb,
                                  WgTe, WuTe, WgTd, WuTd, wxge, wxue, wxgd, wxud,
                                  bge, bue, bgd, bud, prW, prb);

    for (int t = 0; t < 12; ++t) {  // encoder
        cell_gate<<<512, 256, 0, stream>>>(AA, XhT, Hb, WgTe, bge, wxge, x, t, XSgT, 0,
                                           Go, prW, prb, Sgo, Zb, ZhT, R, 0, 0);
        cell_update<<<512, 256, 0, stream>>>(AA, ZhT, Zb, WuTe, bue, wxue, x, t, XSgT, 0,
                                             Sgo, R, H32, Hb, XhT, prW, prb, Go, out, 0);
    }
    for (int t = 0; t < 12; ++t) {  // decoder
        cell_gate<<<512, 256, 0, stream>>>(AA, XhT, Hb, WgTd, bgd, wxgd, ycov, t, XSgT, 768,
                                           Go, prW, prb, Sgo, Zb, ZhT, R, 1, t > 0 ? 1 : 0);
        cell_update<<<512, 256, 0, stream>>>(AA, ZhT, Zb, WuTd, bud, wxud, ycov, t, XSgT, 768,
                                             Sgo, R, H32, Hb, XhT, prW, prb, Go, out, 1);
    }
}

// Round 8
// 2768.796 us; speedup vs baseline: 1.4736x; 1.4736x over previous
//
#include <hip/hip_runtime.h>

// GCRN (AGCRN-style) on gfx950. Inputs/outputs fp32; internal compute bf16 MFMA.
// A = softmax(relu(E E^T)); AA = [A; 2A^2] stacked (T2 = 2A^2 - I folded into
// weights: W0' = W0 - W2).
// Fused cells, two dispatches per cell. Round 8: back to m97-staged K-loops
// (Round 7's per-lane fragment loads scatter 16 rows/instruction — 1.7x
// regression). Occupancy fix: 64-node tiles -> grid 1024 = 4 blocks/CU
// (16 waves/CU) with ~30 KB LDS/block.

typedef __attribute__((ext_vector_type(8))) short bf16x8;
typedef __attribute__((ext_vector_type(4))) float f32x4;
typedef __attribute__((ext_vector_type(4))) unsigned short u16x4;

__device__ __forceinline__ float b2f(unsigned short u) {
    union { unsigned int i; float f; } v; v.i = ((unsigned int)u) << 16; return v.f;
}
__device__ __forceinline__ unsigned short f2b(float f) {
    union { float f; unsigned int i; } v; v.f = f;
    unsigned int r = v.i + 0x7FFFu + ((v.i >> 16) & 1u);
    return (unsigned short)(r >> 16);
}

// LDS dest is wave-uniform base + lane*16 (m104/m108 rule).
#define GLOAD_LDS16(g, l) __builtin_amdgcn_global_load_lds( \
    (const __attribute__((address_space(1))) void*)(g),     \
    (__attribute__((address_space(3))) void*)(l), 16, 0, 0)

// ---------------------------------------------------------------------------
// Generic bf16 GEMM (preamble only): C[m,n] = scale * sum_k P[m,k]*QT[n,k].
// ---------------------------------------------------------------------------
__global__ __launch_bounds__(256) void gemm_bt(
    const unsigned short* __restrict__ P, int lda,
    const unsigned short* __restrict__ QT, int ldb,
    unsigned short* __restrict__ C, int ldc,
    int K, float scale)
{
    __shared__ __align__(16) unsigned short As[128 * 32];
    __shared__ __align__(16) unsigned short Bs[128 * 32];
    const int tid = threadIdx.x;
    const int m0 = blockIdx.y << 7, n0 = blockIdx.x << 7;
    const int w = tid >> 6, l = tid & 63;
    const int wm = (w >> 1) << 6, wn = (w & 1) << 6;
    const int lr = l & 15, lq = l >> 4;
    const int arow = tid >> 2, ak = (tid & 3) << 3;
    f32x4 acc[4][4] = {};

    for (int k0 = 0; k0 < K; k0 += 32) {
#pragma unroll
        for (int p = 0; p < 2; ++p)
            GLOAD_LDS16(P + (size_t)(m0 + arow + (p << 6)) * lda + k0 + ak,
                        &As[((arow + (p << 6)) << 5) + ak]);
#pragma unroll
        for (int p = 0; p < 2; ++p)
            GLOAD_LDS16(QT + (size_t)(n0 + arow + (p << 6)) * ldb + k0 + ak,
                        &Bs[((arow + (p << 6)) << 5) + ak]);
        __syncthreads();
        bf16x8 a[4], b[4];
#pragma unroll
        for (int i = 0; i < 4; ++i)
            a[i] = *(const bf16x8*)&As[((wm + (i << 4) + lr) << 5) + (lq << 3)];
#pragma unroll
        for (int j = 0; j < 4; ++j)
            b[j] = *(const bf16x8*)&Bs[((wn + (j << 4) + lr) << 5) + (lq << 3)];
#pragma unroll
        for (int i = 0; i < 4; ++i)
#pragma unroll
            for (int j = 0; j < 4; ++j)
                acc[i][j] = __builtin_amdgcn_mfma_f32_16x16x32_bf16(a[i], b[j], acc[i][j], 0, 0, 0);
        __syncthreads();
    }
#pragma unroll
    for (int i = 0; i < 4; ++i)
#pragma unroll
        for (int j = 0; j < 4; ++j)
#pragma unroll
            for (int r = 0; r < 4; ++r) {
                const int m = m0 + wm + (i << 4) + (lq << 2) + r;
                const int n = n0 + wn + (j << 4) + lr;
                C[(size_t)m * ldc + n] = f2b(acc[i][j][r] * scale);
            }
}

// ---------------------------------------------------------------------------
// cell_gate: grid 1024 = (b in [0,64)) x (n-tile in [0,16)), 256 threads.
// Phase1: Sh[128][64] = AA[{n0..n0+63, 1024+n0..}] @ XhT[b-rows]^T (staged LDS).
// Phase2: zr = sigmoid([h | Sh_A | Sh_2A2] @ W + bias + corr), M=64 N=128 K=192.
// ---------------------------------------------------------------------------
__global__ __launch_bounds__(256) void cell_gate(
    const unsigned short* __restrict__ AA, const unsigned short* __restrict__ XhT,
    const unsigned short* __restrict__ Hb, const unsigned short* __restrict__ WT,
    const float* __restrict__ bias, const float* __restrict__ wx,
    const float* __restrict__ xin, int t,
    const unsigned short* __restrict__ XSgT, int xsrow,
    const unsigned short* __restrict__ Go,
    const float* __restrict__ prW, const float* __restrict__ prb,
    float* __restrict__ Sgo,
    unsigned short* __restrict__ Zb, unsigned short* __restrict__ ZhT,
    float* __restrict__ R, int dec, int goflag)
{
    __shared__ __align__(16) unsigned short As[128 * 32];   // 8 KB
    __shared__ __align__(16) unsigned short Bs[64 * 32];    // 4 KB
    __shared__ __align__(16) unsigned short Shs[128 * 72];  // 18 KB
    __shared__ float SgoS[128];
    const int tid = threadIdx.x;
    const int b = blockIdx.x >> 4, n0 = (blockIdx.x & 15) << 6;
    const int w = tid >> 6, l = tid & 63;
    const int lr = l & 15, lq = l >> 4;
    const int arow = tid >> 2, ak = (tid & 3) << 3;

    // ---- Phase 1 ----
    {
        const int wm = w << 5;   // wave M base: 0,32,64,96
        f32x4 acc[2][4] = {};
        for (int k0 = 0; k0 < 1024; k0 += 32) {
            GLOAD_LDS16(AA + (size_t)(n0 + arow) * 1024 + k0 + ak,
                        &As[(arow << 5) + ak]);
            GLOAD_LDS16(AA + (size_t)(1024 + n0 + arow) * 1024 + k0 + ak,
                        &As[((64 + arow) << 5) + ak]);
            GLOAD_LDS16(XhT + (size_t)((b << 6) + arow) * 1024 + k0 + ak,
                        &Bs[(arow << 5) + ak]);
            __syncthreads();
            bf16x8 a[2], bb[4];
#pragma unroll
            for (int i = 0; i < 2; ++i)
                a[i] = *(const bf16x8*)&As[((wm + (i << 4) + lr) << 5) + (lq << 3)];
#pragma unroll
            for (int j = 0; j < 4; ++j)
                bb[j] = *(const bf16x8*)&Bs[(((j << 4) + lr) << 5) + (lq << 3)];
#pragma unroll
            for (int i = 0; i < 2; ++i)
#pragma unroll
                for (int j = 0; j < 4; ++j)
                    acc[i][j] = __builtin_amdgcn_mfma_f32_16x16x32_bf16(a[i], bb[j], acc[i][j], 0, 0, 0);
            __syncthreads();
        }
        // Sh -> LDS (bf16); rows 0..63 = A-part, 64..127 = 2A^2-part
#pragma unroll
        for (int i = 0; i < 2; ++i)
#pragma unroll
            for (int j = 0; j < 4; ++j)
#pragma unroll
                for (int r = 0; r < 4; ++r) {
                    const int m = wm + (i << 4) + (lq << 2) + r;
                    const int c = (j << 4) + lr;
                    Shs[m * 72 + c] = f2b(acc[i][j][r]);
                }
        if (dec) {
            float pw[4];
#pragma unroll
            for (int j = 0; j < 4; ++j) pw[j] = prW[(j << 4) + lr];
            const float pb0 = prb[0];
#pragma unroll
            for (int i = 0; i < 2; ++i)
#pragma unroll
                for (int r = 0; r < 4; ++r) {
                    float v = acc[i][0][r] * pw[0] + acc[i][1][r] * pw[1]
                            + acc[i][2][r] * pw[2] + acc[i][3][r] * pw[3];
                    v += __shfl_down(v, 8, 16);
                    v += __shfl_down(v, 4, 16);
                    v += __shfl_down(v, 2, 16);
                    v += __shfl_down(v, 1, 16);
                    if (lr == 0) {
                        const int m = wm + (i << 4) + (lq << 2) + r;
                        const int grow = (m < 64) ? (n0 + m) : (960 + n0 + m);
                        // t=0: GO token is zero -> A@go = 0 (goflag==0)
                        const float val = goflag
                            ? (v + pb0 * ((m < 64) ? 1.f : 2.f)) : 0.f;
                        Sgo[(size_t)grow * 64 + b] = val;
                        SgoS[m] = val;
                    }
                }
        }
    }
    __syncthreads();   // Shs/SgoS ready

    // ---- Phase 2: M=64, N=128, K=192 ----
    const int wm2 = (w >> 1) << 5, wn2 = (w & 1) << 6;
    f32x4 acc2[2][4] = {};
    for (int kk0 = 0; kk0 < 192; kk0 += 32) {
        bf16x8 a[2], bb[4];
        if (kk0 < 64) {
#pragma unroll
            for (int i = 0; i < 2; ++i)
                a[i] = *(const bf16x8*)(Hb + ((size_t)(b << 10) + n0 + wm2 + (i << 4) + lr) * 64 + kk0 + (lq << 3));
        } else {
            const int rowb = (kk0 >= 128) ? 64 : 0;
            const int c0 = kk0 & 63;
#pragma unroll
            for (int i = 0; i < 2; ++i)
                a[i] = *(const bf16x8*)&Shs[(rowb + wm2 + (i << 4) + lr) * 72 + c0 + (lq << 3)];
        }
#pragma unroll
        for (int j = 0; j < 4; ++j)
            bb[j] = *(const bf16x8*)(WT + (size_t)(wn2 + (j << 4) + lr) * 192 + kk0 + (lq << 3));
#pragma unroll
        for (int i = 0; i < 2; ++i)
#pragma unroll
            for (int j = 0; j < 4; ++j)
                acc2[i][j] = __builtin_amdgcn_mfma_f32_16x16x32_bf16(a[i], bb[j], acc2[i][j], 0, 0, 0);
    }

#pragma unroll
    for (int i = 0; i < 2; ++i) {
        const int nb_loc = wm2 + (i << 4) + (lq << 2);      // local node 0..63
        const int node_base = n0 + nb_loc;
        float c0[4], c1[4], c2[4], c3[4], c4[4], c5[4];
        for (int r = 0; r < 4; ++r) {
            const int node = node_base + r;
            if (!dec) {
                c0[r] = xin[((b * 12 + t) << 10) + node];
                c1[r] = b2f(XSgT[(size_t)(xsrow + t * 64 + b) * 2048 + node]);
                c2[r] = b2f(XSgT[(size_t)(xsrow + t * 64 + b) * 2048 + 1024 + node]);
                c3[r] = c4[r] = c5[r] = 0.f;
            } else {
                c0[r] = b2f(Go[(b << 10) + node]);
                c1[r] = xin[((b * 12 + t) << 10) + node];
                c2[r] = SgoS[nb_loc + r];
                c3[r] = b2f(XSgT[(size_t)(xsrow + t * 64 + b) * 2048 + node]);
                c4[r] = SgoS[64 + nb_loc + r];
                c5[r] = b2f(XSgT[(size_t)(xsrow + t * 64 + b) * 2048 + 1024 + node]);
            }
        }
#pragma unroll
        for (int j = 0; j < 4; ++j) {
            const int jc = wn2 + (j << 4) + lr;
            const float bj = bias[jc];
            const float w0 = wx[jc], w1 = wx[128 + jc], w2 = wx[256 + jc];
            float w3 = 0.f, w4 = 0.f, w5 = 0.f;
            if (dec) { w3 = wx[384 + jc]; w4 = wx[512 + jc]; w5 = wx[640 + jc]; }
            if (jc < 64) {
                u16x4 pack;
                for (int r = 0; r < 4; ++r) {
                    float v = acc2[i][j][r] + bj + c0[r] * w0 + c1[r] * w1 + c2[r] * w2
                              + c3[r] * w3 + c4[r] * w4 + c5[r] * w5;
                    float g = 1.f / (1.f + __expf(-v));
                    const int node = node_base + r;
                    const size_t idx = ((size_t)(b << 10) + node) * 64 + jc;
                    float zh = g * b2f(Hb[idx]);   // bf16 h (zh re-rounded anyway)
                    unsigned short zb = f2b(zh);
                    Zb[idx] = zb;
                    pack[r] = zb;
                }
                *(u16x4*)&ZhT[(size_t)((b << 6) + jc) * 1024 + node_base] = pack;
            } else {
                for (int r = 0; r < 4; ++r) {
                    float v = acc2[i][j][r] + bj + c0[r] * w0 + c1[r] * w1 + c2[r] * w2
                              + c3[r] * w3 + c4[r] * w4 + c5[r] * w5;
                    float g = 1.f / (1.f + __expf(-v));
                    const int node = node_base + r;
                    R[((size_t)(b << 10) + node) * 64 + (jc - 64)] = g;
                }
            }
        }
    }
}

// ---------------------------------------------------------------------------
// cell_update: grid 1024 = (b, n-tile), 256 threads.
// ---------------------------------------------------------------------------
__global__ __launch_bounds__(256) void cell_update(
    const unsigned short* __restrict__ AA, const unsigned short* __restrict__ ZhT,
    const unsigned short* __restrict__ Zb, const unsigned short* __restrict__ WT,
    const float* __restrict__ bias, const float* __restrict__ wx,
    const float* __restrict__ xin, int t,
    const unsigned short* __restrict__ XSgT, int xsrow,
    const float* __restrict__ Sgo, const float* __restrict__ Rg,
    float* __restrict__ H32, unsigned short* __restrict__ Hb,
    unsigned short* __restrict__ XhT,
    const float* __restrict__ prW, const float* __restrict__ prb,
    unsigned short* __restrict__ Go, float* __restrict__ outp, int dec)
{
    __shared__ __align__(16) unsigned short As[128 * 32];   // 8 KB
    __shared__ __align__(16) unsigned short Bs[64 * 32];    // 4 KB
    __shared__ __align__(16) unsigned short Shs[128 * 72];  // 18 KB
    const int tid = threadIdx.x;
    const int b = blockIdx.x >> 4, n0 = (blockIdx.x & 15) << 6;
    const int w = tid >> 6, l = tid & 63;
    const int lr = l & 15, lq = l >> 4;
    const int arow = tid >> 2, ak = (tid & 3) << 3;

    // ---- Phase 1: Sz[128][64] = AA @ ZhT[b-rows]^T ----
    {
        const int wm = w << 5;
        f32x4 acc[2][4] = {};
        for (int k0 = 0; k0 < 1024; k0 += 32) {
            GLOAD_LDS16(AA + (size_t)(n0 + arow) * 1024 + k0 + ak,
                        &As[(arow << 5) + ak]);
            GLOAD_LDS16(AA + (size_t)(1024 + n0 + arow) * 1024 + k0 + ak,
                        &As[((64 + arow) << 5) + ak]);
            GLOAD_LDS16(ZhT + (size_t)((b << 6) + arow) * 1024 + k0 + ak,
                        &Bs[(arow << 5) + ak]);
            __syncthreads();
            bf16x8 a[2], bb[4];
#pragma unroll
            for (int i = 0; i < 2; ++i)
                a[i] = *(const bf16x8*)&As[((wm + (i << 4) + lr) << 5) + (lq << 3)];
#pragma unroll
            for (int j = 0; j < 4; ++j)
                bb[j] = *(const bf16x8*)&Bs[(((j << 4) + lr) << 5) + (lq << 3)];
#pragma unroll
            for (int i = 0; i < 2; ++i)
#pragma unroll
                for (int j = 0; j < 4; ++j)
                    acc[i][j] = __builtin_amdgcn_mfma_f32_16x16x32_bf16(a[i], bb[j], acc[i][j], 0, 0, 0);
            __syncthreads();
        }
#pragma unroll
        for (int i = 0; i < 2; ++i)
#pragma unroll
            for (int j = 0; j < 4; ++j)
#pragma unroll
                for (int r = 0; r < 4; ++r) {
                    const int m = wm + (i << 4) + (lq << 2) + r;
                    const int c = (j << 4) + lr;
                    Shs[m * 72 + c] = f2b(acc[i][j][r]);
                }
    }
    __syncthreads();

    // ---- Phase 2: M=64, N=64, K=192 ----
    const int wm2 = w << 4;   // 0,16,32,48
    f32x4 acc2[4] = {};
    for (int kk0 = 0; kk0 < 192; kk0 += 32) {
        bf16x8 a, bb[4];
        if (kk0 < 64) {
            a = *(const bf16x8*)(Zb + ((size_t)(b << 10) + n0 + wm2 + lr) * 64 + kk0 + (lq << 3));
        } else {
            const int rowb = (kk0 >= 128) ? 64 : 0;
            const int c0 = kk0 & 63;
            a = *(const bf16x8*)&Shs[(rowb + wm2 + lr) * 72 + c0 + (lq << 3)];
        }
#pragma unroll
        for (int j = 0; j < 4; ++j)
            bb[j] = *(const bf16x8*)(WT + (size_t)((j << 4) + lr) * 192 + kk0 + (lq << 3));
#pragma unroll
        for (int j = 0; j < 4; ++j)
            acc2[j] = __builtin_amdgcn_mfma_f32_16x16x32_bf16(a, bb[j], acc2[j], 0, 0, 0);
    }

    float pw[4];
    if (dec) {
#pragma unroll
        for (int j = 0; j < 4; ++j) pw[j] = prW[(j << 4) + lr];
    }

    {
        const int node_base = n0 + wm2 + (lq << 2);
        float c0[4], c1[4], c2[4], c3[4], c4[4], c5[4];
        for (int r = 0; r < 4; ++r) {
            const int node = node_base + r;
            if (!dec) {
                c0[r] = xin[((b * 12 + t) << 10) + node];
                c1[r] = b2f(XSgT[(size_t)(xsrow + t * 64 + b) * 2048 + node]);
                c2[r] = b2f(XSgT[(size_t)(xsrow + t * 64 + b) * 2048 + 1024 + node]);
                c3[r] = c4[r] = c5[r] = 0.f;
            } else {
                c0[r] = b2f(Go[(b << 10) + node]);
                c1[r] = xin[((b * 12 + t) << 10) + node];
                c2[r] = Sgo[(size_t)node * 64 + b];
                c3[r] = b2f(XSgT[(size_t)(xsrow + t * 64 + b) * 2048 + node]);
                c4[r] = Sgo[(size_t)(1024 + node) * 64 + b];
                c5[r] = b2f(XSgT[(size_t)(xsrow + t * 64 + b) * 2048 + 1024 + node]);
            }
        }
        float psum[4] = {0.f, 0.f, 0.f, 0.f};
#pragma unroll
        for (int j = 0; j < 4; ++j) {
            const int jc = (j << 4) + lr;
            const float bj = bias[jc];
            const float w0 = wx[jc], w1 = wx[64 + jc], w2 = wx[128 + jc];
            float w3 = 0.f, w4 = 0.f, w5 = 0.f;
            if (dec) { w3 = wx[192 + jc]; w4 = wx[256 + jc]; w5 = wx[320 + jc]; }
            u16x4 pack;
            for (int r = 0; r < 4; ++r) {
                float v = acc2[j][r] + bj + c0[r] * w0 + c1[r] * w1 + c2[r] * w2
                          + c3[r] * w3 + c4[r] * w4 + c5[r] * w5;
                float hc = tanhf(v);
                const int node = node_base + r;
                const size_t idx = ((size_t)(b << 10) + node) * 64 + jc;
                float rr = Rg[idx];
                float hn = rr * H32[idx] + (1.f - rr) * hc;
                H32[idx] = hn;
                unsigned short hb = f2b(hn);
                Hb[idx] = hb;
                pack[r] = hb;
                if (dec) psum[r] += hn * pw[j];
            }
            *(u16x4*)&XhT[(size_t)((b << 6) + jc) * 1024 + node_base] = pack;
        }
        if (dec) {
#pragma unroll
            for (int r = 0; r < 4; ++r) {
                float v = psum[r];
                v += __shfl_down(v, 8, 16);
                v += __shfl_down(v, 4, 16);
                v += __shfl_down(v, 2, 16);
                v += __shfl_down(v, 1, 16);
                if (lr == 0) {
                    const int node = node_base + r;
                    const float go = v + prb[0];
                    Go[(b << 10) + node] = f2b(go);
                    outp[((size_t)(b * 12 + t) << 10) + node] = go;
                }
            }
        }
    }
}

// ---------------------------------------------------------------------------
__global__ __launch_bounds__(256) void adj_softmax(
    const float* __restrict__ E, unsigned short* __restrict__ A)
{
    __shared__ float Es[8192];
    __shared__ float vals[1024];
    __shared__ float red[8];
    const int tid = threadIdx.x;
    const int r = blockIdx.x;
    for (int i = tid; i < 8192; i += 256) Es[i] = E[i];
    __syncthreads();
    float er[8];
#pragma unroll
    for (int e = 0; e < 8; ++e) er[e] = Es[(r << 3) + e];
    float lmax = -1e30f;
    for (int c = tid; c < 1024; c += 256) {
        float s = 0.f;
#pragma unroll
        for (int e = 0; e < 8; ++e) s += er[e] * Es[(c << 3) + e];
        s = fmaxf(s, 0.f);
        vals[c] = s;
        lmax = fmaxf(lmax, s);
    }
    for (int off = 32; off; off >>= 1) lmax = fmaxf(lmax, __shfl_down(lmax, off, 64));
    if ((tid & 63) == 0) red[tid >> 6] = lmax;
    __syncthreads();
    const float m = fmaxf(fmaxf(red[0], red[1]), fmaxf(red[2], red[3]));
    float lsum = 0.f;
    for (int c = tid; c < 1024; c += 256) {
        float e = __expf(vals[c] - m);
        vals[c] = e;
        lsum += e;
    }
    for (int off = 32; off; off >>= 1) lsum += __shfl_down(lsum, off, 64);
    if ((tid & 63) == 0) red[4 + (tid >> 6)] = lsum;
    __syncthreads();
    const float inv = 1.f / (red[4] + red[5] + red[6] + red[7]);
    for (int c = tid; c < 1024; c += 256)
        A[(r << 10) + c] = f2b(vals[c] * inv);
}

__global__ __launch_bounds__(256) void transpose_bf16(
    const unsigned short* __restrict__ src, unsigned short* __restrict__ dst)
{
    __shared__ unsigned short tile[64][65];
    const int bx = blockIdx.x & 15, by = blockIdx.x >> 4;
    const int x0 = bx << 6, y0 = by << 6;
    for (int i = threadIdx.x; i < 4096; i += 256) {
        const int r = i >> 6, c = i & 63;
        tile[r][c] = src[((y0 + r) << 10) + x0 + c];
    }
    __syncthreads();
    for (int i = threadIdx.x; i < 4096; i += 256) {
        const int r = i >> 6, c = i & 63;
        dst[((x0 + r) << 10) + y0 + c] = tile[c][r];
    }
}

__global__ __launch_bounds__(256) void build_xall(
    const float* __restrict__ x, const float* __restrict__ y,
    unsigned short* __restrict__ XallT)
{
    const int id = blockIdx.x * 256 + threadIdx.x;
    const int row = id >> 10, n = id & 1023;
    int t, b;
    const float* src;
    if (row < 768) { t = row >> 6; b = row & 63; src = x; }
    else { const int rr = row - 768; t = rr >> 6; b = rr & 63; src = y; }
    XallT[id] = f2b(src[((b * 12 + t) << 10) + n]);
}

__global__ __launch_bounds__(256) void wprep(
    const float* egW, const float* egb,
    const float* euW, const float* eub,
    const float* dgW, const float* dgb,
    const float* duW, const float* dub,
    const float* pW, const float* pb,
    unsigned short* WgTe, unsigned short* WuTe, unsigned short* WgTd, unsigned short* WuTd,
    float* wxge, float* wxue, float* wxgd, float* wxud,
    float* bge, float* bue, float* bgd, float* bud,
    float* projW, float* projb)
{
    const int tid0 = blockIdx.x * 256 + threadIdx.x;
    const int stride = 256 * gridDim.x;
    for (int i = tid0; i < 128 * 192; i += stride) {
        const int j = i / 192, kk = i % 192, k = kk >> 6, c = kk & 63;
        float v = egW[(k * 65 + 1 + c) * 128 + j];
        if (k == 0) v -= egW[(131 + c) * 128 + j];
        WgTe[i] = f2b(v);
    }
    for (int i = tid0; i < 64 * 192; i += stride) {
        const int j = i / 192, kk = i % 192, k = kk >> 6, c = kk & 63;
        float v = euW[(k * 65 + 1 + c) * 64 + j];
        if (k == 0) v -= euW[(131 + c) * 64 + j];
        WuTe[i] = f2b(v);
    }
    for (int i = tid0; i < 128 * 192; i += stride) {
        const int j = i / 192, kk = i % 192, k = kk >> 6, c = kk & 63;
        float v = dgW[(k * 66 + 2 + c) * 128 + j];
        if (k == 0) v -= dgW[(134 + c) * 128 + j];
        WgTd[i] = f2b(v);
    }
    for (int i = tid0; i < 64 * 192; i += stride) {
        const int j = i / 192, kk = i % 192, k = kk >> 6, c = kk & 63;
        float v = duW[(k * 66 + 2 + c) * 64 + j];
        if (k == 0) v -= duW[(134 + c) * 64 + j];
        WuTd[i] = f2b(v);
    }
    for (int i = tid0; i < 384; i += stride) {
        const int k = i >> 7, j = i & 127;
        float v;
        if (k == 0) v = egW[j] - egW[130 * 128 + j];
        else if (k == 1) v = egW[65 * 128 + j];
        else v = egW[130 * 128 + j];
        wxge[i] = v;
    }
    for (int i = tid0; i < 192; i += stride) {
        const int k = i >> 6, j = i & 63;
        float v;
        if (k == 0) v = euW[j] - euW[130 * 64 + j];
        else if (k == 1) v = euW[65 * 64 + j];
        else v = euW[130 * 64 + j];
        wxue[i] = v;
    }
    for (int i = tid0; i < 768; i += stride) {
        const int k = i >> 7, j = i & 127;
        float v;
        switch (k) {
            case 0: v = dgW[j] - dgW[132 * 128 + j]; break;
            case 1: v = dgW[128 + j] - dgW[133 * 128 + j]; break;
            case 2: v = dgW[66 * 128 + j]; break;
            case 3: v = dgW[67 * 128 + j]; break;
            case 4: v = dgW[132 * 128 + j]; break;
            default: v = dgW[133 * 128 + j]; break;
        }
        wxgd[i] = v;
    }
    for (int i = tid0; i < 384; i += stride) {
        const int k = i >> 6, j = i & 63;
        float v;
        switch (k) {
            case 0: v = duW[j] - duW[132 * 64 + j]; break;
            case 1: v = duW[64 + j] - duW[133 * 64 + j]; break;
            case 2: v = duW[66 * 64 + j]; break;
            case 3: v = duW[67 * 64 + j]; break;
            case 4: v = duW[132 * 64 + j]; break;
            default: v = duW[133 * 64 + j]; break;
        }
        wxud[i] = v;
    }
    for (int i = tid0; i < 128; i += stride) bge[i] = egb[i];
    for (int i = tid0; i < 64; i += stride) bue[i] = eub[i];
    for (int i = tid0; i < 128; i += stride) bgd[i] = dgb[i];
    for (int i = tid0; i < 64; i += stride) bud[i] = dub[i];
    for (int i = tid0; i < 64; i += stride) projW[i] = pW[i];
    if (tid0 == 0) projb[0] = pb[0];
}

// ---------------------------------------------------------------------------
extern "C" void kernel_launch(void* const* d_in, const int* in_sizes, int n_in,
                              void* d_out, int out_size, void* d_ws, size_t ws_size,
                              hipStream_t stream)
{
    (void)in_sizes; (void)n_in; (void)out_size; (void)ws_size;
    const float* x    = (const float*)d_in[0];
    const float* ycov = (const float*)d_in[1];
    const float* E    = (const float*)d_in[2];
    const float* egW  = (const float*)d_in[3];
    const float* egb  = (const float*)d_in[4];
    const float* euW  = (const float*)d_in[5];
    const float* eub  = (const float*)d_in[6];
    const float* dgW  = (const float*)d_in[7];
    const float* dgb  = (const float*)d_in[8];
    const float* duW  = (const float*)d_in[9];
    const float* dub  = (const float*)d_in[10];
    const float* pW   = (const float*)d_in[11];
    const float* pb   = (const float*)d_in[12];
    float* out = (float*)d_out;

    size_t off = 0;
    auto carve = [&](size_t bytes) -> void* {
        void* p = (char*)d_ws + off;
        off += (bytes + 255) & ~(size_t)255;
        return p;
    };
    unsigned short* AA    = (unsigned short*)carve(2048ull * 1024 * 2); // [A; 2A^2]
    unsigned short* XSgT  = (unsigned short*)carve(1536ull * 2048 * 2);
    unsigned short* XhT   = (unsigned short*)carve(4096ull * 1024 * 2);
    unsigned short* ZhT   = (unsigned short*)carve(4096ull * 1024 * 2);
    unsigned short* Hb    = (unsigned short*)carve(65536ull * 64 * 2);
    float*          H32   = (float*)carve(65536ull * 64 * 4);
    unsigned short* Zb    = (unsigned short*)carve(65536ull * 64 * 2);
    float*          R     = (float*)carve(65536ull * 64 * 4);
    float*          Sgo   = (float*)carve(2048ull * 64 * 4);
    unsigned short* Go    = (unsigned short*)carve(65536ull * 2);
    unsigned short* WgTe  = (unsigned short*)carve(128ull * 192 * 2);
    unsigned short* WuTe  = (unsigned short*)carve(64ull * 192 * 2);
    unsigned short* WgTd  = (unsigned short*)carve(128ull * 192 * 2);
    unsigned short* WuTd  = (unsigned short*)carve(64ull * 192 * 2);
    float* wxge = (float*)carve(384 * 4);
    float* wxue = (float*)carve(192 * 4);
    float* wxgd = (float*)carve(768 * 4);
    float* wxud = (float*)carve(384 * 4);
    float* bge  = (float*)carve(128 * 4);
    float* bue  = (float*)carve(64 * 4);
    float* bgd  = (float*)carve(128 * 4);
    float* bud  = (float*)carve(64 * 4);
    float* prW  = (float*)carve(64 * 4);
    float* prb  = (float*)carve(4);
    // Aliases: AT and XallT live inside Zb (both consumed before Zb's first write).
    unsigned short* AT    = Zb;
    unsigned short* XallT = Zb + 1024ull * 1024;

    hipMemsetAsync(XhT, 0, 4096ull * 1024 * 2, stream);
    hipMemsetAsync(Hb, 0, 65536ull * 64 * 2, stream);
    hipMemsetAsync(H32, 0, 65536ull * 64 * 4, stream);
    hipMemsetAsync(Go, 0, 65536ull * 2, stream);

    adj_softmax<<<1024, 256, 0, stream>>>(E, AA);
    transpose_bf16<<<256, 256, 0, stream>>>(AA, AT);
    gemm_bt<<<dim3(8, 8), 256, 0, stream>>>(AA, 1024, AT, 1024, AA + 1024 * 1024, 1024, 1024, 2.0f);
    build_xall<<<6144, 256, 0, stream>>>(x, ycov, XallT);
    gemm_bt<<<dim3(16, 12), 256, 0, stream>>>(XallT, 1024, AA, 1024, XSgT, 2048, 1024, 1.0f);
    wprep<<<64, 256, 0, stream>>>(egW, egb, euW, eub, dgW, dgb, duW, dub, pW, pb,
                                  WgTe, WuTe, WgTd, WuTd, wxge, wxue, wxgd, wxud,
                                  bge, bue, bgd, bud, prW, prb);

    for (int t = 0; t < 12; ++t) {  // encoder
        cell_gate<<<1024, 256, 0, stream>>>(AA, XhT, Hb, WgTe, bge, wxge, x, t, XSgT, 0,
                                            Go, prW, prb, Sgo, Zb, ZhT, R, 0, 0);
        cell_update<<<1024, 256, 0, stream>>>(AA, ZhT, Zb, WuTe, bue, wxue, x, t, XSgT, 0,
                                              Sgo, R, H32, Hb, XhT, prW, prb, Go, out, 0);
    }
    for (int t = 0; t < 12; ++t) {  // decoder
        cell_gate<<<1024, 256, 0, stream>>>(AA, XhT, Hb, WgTd, bgd, wxgd, ycov, t, XSgT, 768,
                                            Go, prW, prb, Sgo, Zb, ZhT, R, 1, t > 0 ? 1 : 0);
        cell_update<<<1024, 256, 0, stream>>>(AA, ZhT, Zb, WuTd, bud, wxud, ycov, t, XSgT, 768,
                                              Sgo, R, H32, Hb, XhT, prW, prb, Go, out, 1);
    }
}

// Round 9
// 2528.560 us; speedup vs baseline: 1.6136x; 1.0950x over previous
//
#include <hip/hip_runtime.h>

// GCRN (AGCRN-style) on gfx950. Inputs/outputs fp32; internal compute bf16 MFMA.
// A = softmax(relu(E E^T)); AA = [A; 2A^2] stacked (T2 = 2A^2 - I folded into
// weights: W0' = W0 - W2).
// Round 9: R6 structure (128-node tiles, 512 blocks, staged phase-1) with
// LDS UNION: phase-1 staging (As+Bs, 20.5 KB) aliases the Shs transpose buffer
// (37 KB) since their lifetimes are disjoint -> 37.9 KB/block -> 4 blocks/CU
// (was 61.4 KB -> 2). Phase-2 uses per-lane loads (WT/Hb/Zb are small/L1-hot).
// h state bf16-only (H32 dropped), R gate bf16 -> ~50 MB less HBM per cell.

typedef __attribute__((ext_vector_type(8))) short bf16x8;
typedef __attribute__((ext_vector_type(4))) float f32x4;
typedef __attribute__((ext_vector_type(4))) unsigned short u16x4;

__device__ __forceinline__ float b2f(unsigned short u) {
    union { unsigned int i; float f; } v; v.i = ((unsigned int)u) << 16; return v.f;
}
__device__ __forceinline__ unsigned short f2b(float f) {
    union { float f; unsigned int i; } v; v.f = f;
    unsigned int r = v.i + 0x7FFFu + ((v.i >> 16) & 1u);
    return (unsigned short)(r >> 16);
}

// LDS dest is wave-uniform base + lane*16 (m104/m108 rule).
#define GLOAD_LDS16(g, l) __builtin_amdgcn_global_load_lds( \
    (const __attribute__((address_space(1))) void*)(g),     \
    (__attribute__((address_space(3))) void*)(l), 16, 0, 0)

// ---------------------------------------------------------------------------
// Generic bf16 GEMM (preamble only): C[m,n] = scale * sum_k P[m,k]*QT[n,k].
// ---------------------------------------------------------------------------
__global__ __launch_bounds__(256) void gemm_bt(
    const unsigned short* __restrict__ P, int lda,
    const unsigned short* __restrict__ QT, int ldb,
    unsigned short* __restrict__ C, int ldc,
    int K, float scale)
{
    __shared__ __align__(16) unsigned short As[128 * 32];
    __shared__ __align__(16) unsigned short Bs[128 * 32];
    const int tid = threadIdx.x;
    const int m0 = blockIdx.y << 7, n0 = blockIdx.x << 7;
    const int w = tid >> 6, l = tid & 63;
    const int wm = (w >> 1) << 6, wn = (w & 1) << 6;
    const int lr = l & 15, lq = l >> 4;
    const int arow = tid >> 2, ak = (tid & 3) << 3;
    f32x4 acc[4][4] = {};

    for (int k0 = 0; k0 < K; k0 += 32) {
#pragma unroll
        for (int p = 0; p < 2; ++p)
            GLOAD_LDS16(P + (size_t)(m0 + arow + (p << 6)) * lda + k0 + ak,
                        &As[((arow + (p << 6)) << 5) + ak]);
#pragma unroll
        for (int p = 0; p < 2; ++p)
            GLOAD_LDS16(QT + (size_t)(n0 + arow + (p << 6)) * ldb + k0 + ak,
                        &Bs[((arow + (p << 6)) << 5) + ak]);
        __syncthreads();
        bf16x8 a[4], b[4];
#pragma unroll
        for (int i = 0; i < 4; ++i)
            a[i] = *(const bf16x8*)&As[((wm + (i << 4) + lr) << 5) + (lq << 3)];
#pragma unroll
        for (int j = 0; j < 4; ++j)
            b[j] = *(const bf16x8*)&Bs[((wn + (j << 4) + lr) << 5) + (lq << 3)];
#pragma unroll
        for (int i = 0; i < 4; ++i)
#pragma unroll
            for (int j = 0; j < 4; ++j)
                acc[i][j] = __builtin_amdgcn_mfma_f32_16x16x32_bf16(a[i], b[j], acc[i][j], 0, 0, 0);
        __syncthreads();
    }
#pragma unroll
    for (int i = 0; i < 4; ++i)
#pragma unroll
        for (int j = 0; j < 4; ++j)
#pragma unroll
            for (int r = 0; r < 4; ++r) {
                const int m = m0 + wm + (i << 4) + (lq << 2) + r;
                const int n = n0 + wn + (j << 4) + lr;
                C[(size_t)m * ldc + n] = f2b(acc[i][j][r] * scale);
            }
}

// ---------------------------------------------------------------------------
// cell_gate: grid 512 = (b in [0,64)) x (n0-tile in [0,8)), 256 threads.
// LDS union: [phase1: As 256x32 | Bs 64x32] aliased with [Shs 256x72 | SgoS].
// ---------------------------------------------------------------------------
__global__ __launch_bounds__(256, 4) void cell_gate(
    const unsigned short* __restrict__ AA, const unsigned short* __restrict__ XhT,
    const unsigned short* __restrict__ Hb, const unsigned short* __restrict__ WT,
    const float* __restrict__ bias, const float* __restrict__ wx,
    const float* __restrict__ xin, int t,
    const unsigned short* __restrict__ XSgT, int xsrow,
    const unsigned short* __restrict__ Go,
    const float* __restrict__ prW, const float* __restrict__ prb,
    float* __restrict__ Sgo,
    unsigned short* __restrict__ Zb, unsigned short* __restrict__ ZhT,
    unsigned short* __restrict__ R, int dec, int goflag)
{
    __shared__ __align__(16) unsigned char smem[37888];
    unsigned short* As  = (unsigned short*)smem;            // 256*32 = 16 KB
    unsigned short* Bs  = (unsigned short*)(smem + 16384);  // 64*32  =  4 KB
    unsigned short* Shs = (unsigned short*)smem;            // 256*72 = 36 KB
    float* SgoS = (float*)(smem + 36864);                   // 256 floats
    const int tid = threadIdx.x;
    const int b = blockIdx.x >> 3, n0 = (blockIdx.x & 7) << 7;
    const int w = tid >> 6, l = tid & 63;
    const int lr = l & 15, lq = l >> 4;
    const int arow = tid >> 2, ak = (tid & 3) << 3;

    // ---- Phase 1: Sh[256][64] = AA[{n0..n0+127, 1024+n0..}] @ XhT[b-rows]^T
    {
        const int wm = w << 6;   // wave M base: 0,64,128,192
        f32x4 acc[4][4] = {};
        for (int k0 = 0; k0 < 1024; k0 += 32) {
#pragma unroll
            for (int p = 0; p < 4; ++p) {
                const int row = arow + (p << 6);
                const int grow = (p < 2) ? (n0 + row) : (896 + n0 + row);
                GLOAD_LDS16(AA + (size_t)grow * 1024 + k0 + ak, &As[(row << 5) + ak]);
            }
            GLOAD_LDS16(XhT + (size_t)((b << 6) + arow) * 1024 + k0 + ak,
                        &Bs[(arow << 5) + ak]);
            __syncthreads();
            bf16x8 a[4], bb[4];
#pragma unroll
            for (int i = 0; i < 4; ++i)
                a[i] = *(const bf16x8*)&As[((wm + (i << 4) + lr) << 5) + (lq << 3)];
#pragma unroll
            for (int j = 0; j < 4; ++j)
                bb[j] = *(const bf16x8*)&Bs[(((j << 4) + lr) << 5) + (lq << 3)];
#pragma unroll
            for (int i = 0; i < 4; ++i)
#pragma unroll
                for (int j = 0; j < 4; ++j)
                    acc[i][j] = __builtin_amdgcn_mfma_f32_16x16x32_bf16(a[i], bb[j], acc[i][j], 0, 0, 0);
            __syncthreads();   // all LDS reads done -> safe to alias As/Bs below
        }
        // Sh -> LDS (bf16), overwriting the staging region (lifetimes disjoint)
#pragma unroll
        for (int i = 0; i < 4; ++i)
#pragma unroll
            for (int j = 0; j < 4; ++j)
#pragma unroll
                for (int r = 0; r < 4; ++r) {
                    const int m = wm + (i << 4) + (lq << 2) + r;
                    const int c = (j << 4) + lr;
                    Shs[m * 72 + c] = f2b(acc[i][j][r]);
                }
        if (dec) {
            float pw[4];
#pragma unroll
            for (int j = 0; j < 4; ++j) pw[j] = prW[(j << 4) + lr];
            const float pb0 = prb[0];
#pragma unroll
            for (int i = 0; i < 4; ++i)
#pragma unroll
                for (int r = 0; r < 4; ++r) {
                    float v = acc[i][0][r] * pw[0] + acc[i][1][r] * pw[1]
                            + acc[i][2][r] * pw[2] + acc[i][3][r] * pw[3];
                    v += __shfl_down(v, 8, 16);
                    v += __shfl_down(v, 4, 16);
                    v += __shfl_down(v, 2, 16);
                    v += __shfl_down(v, 1, 16);
                    if (lr == 0) {
                        const int m = wm + (i << 4) + (lq << 2) + r;
                        const int grow = (m < 128) ? (n0 + m) : (896 + n0 + m);
                        // t=0: GO token is zero -> A@go = 0 (goflag==0)
                        const float val = goflag
                            ? (v + pb0 * ((m < 128) ? 1.f : 2.f)) : 0.f;
                        Sgo[(size_t)grow * 64 + b] = val;
                        SgoS[m] = val;
                    }
                }
        }
    }
    __syncthreads();   // Shs/SgoS ready for all waves

    // ---- Phase 2: zr = sigmoid([h | Sh_A | Sh_2A2] @ W + bias + corr) ----
    const int wm2 = (w >> 1) << 6, wn2 = (w & 1) << 6;
    f32x4 acc2[4][4] = {};
    for (int kk0 = 0; kk0 < 192; kk0 += 32) {
        bf16x8 a[4], bb[4];
        if (kk0 < 64) {
#pragma unroll
            for (int i = 0; i < 4; ++i)
                a[i] = *(const bf16x8*)(Hb + ((size_t)(b << 10) + n0 + wm2 + (i << 4) + lr) * 64 + kk0 + (lq << 3));
        } else {
            const int rowb = (kk0 >= 128) ? 128 : 0;
            const int c0 = kk0 & 63;
#pragma unroll
            for (int i = 0; i < 4; ++i)
                a[i] = *(const bf16x8*)&Shs[(rowb + wm2 + (i << 4) + lr) * 72 + c0 + (lq << 3)];
        }
#pragma unroll
        for (int j = 0; j < 4; ++j)
            bb[j] = *(const bf16x8*)(WT + (size_t)(wn2 + (j << 4) + lr) * 192 + kk0 + (lq << 3));
#pragma unroll
        for (int i = 0; i < 4; ++i)
#pragma unroll
            for (int j = 0; j < 4; ++j)
                acc2[i][j] = __builtin_amdgcn_mfma_f32_16x16x32_bf16(a[i], bb[j], acc2[i][j], 0, 0, 0);
    }

#pragma unroll
    for (int i = 0; i < 4; ++i) {
        const int nb_loc = wm2 + (i << 4) + (lq << 2);      // local node 0..127
        const int node_base = n0 + nb_loc;
        float c0[4], c1[4], c2[4], c3[4], c4[4], c5[4];
        for (int r = 0; r < 4; ++r) {
            const int node = node_base + r;
            if (!dec) {
                c0[r] = xin[((b * 12 + t) << 10) + node];
                c1[r] = b2f(XSgT[(size_t)(xsrow + t * 64 + b) * 2048 + node]);
                c2[r] = b2f(XSgT[(size_t)(xsrow + t * 64 + b) * 2048 + 1024 + node]);
                c3[r] = c4[r] = c5[r] = 0.f;
            } else {
                c0[r] = b2f(Go[(b << 10) + node]);
                c1[r] = xin[((b * 12 + t) << 10) + node];
                c2[r] = SgoS[nb_loc + r];
                c3[r] = b2f(XSgT[(size_t)(xsrow + t * 64 + b) * 2048 + node]);
                c4[r] = SgoS[128 + nb_loc + r];
                c5[r] = b2f(XSgT[(size_t)(xsrow + t * 64 + b) * 2048 + 1024 + node]);
            }
        }
#pragma unroll
        for (int j = 0; j < 4; ++j) {
            const int jc = wn2 + (j << 4) + lr;
            const float bj = bias[jc];
            const float w0 = wx[jc], w1 = wx[128 + jc], w2 = wx[256 + jc];
            float w3 = 0.f, w4 = 0.f, w5 = 0.f;
            if (dec) { w3 = wx[384 + jc]; w4 = wx[512 + jc]; w5 = wx[640 + jc]; }
            if (jc < 64) {
                u16x4 pack;
                for (int r = 0; r < 4; ++r) {
                    float v = acc2[i][j][r] + bj + c0[r] * w0 + c1[r] * w1 + c2[r] * w2
                              + c3[r] * w3 + c4[r] * w4 + c5[r] * w5;
                    float g = 1.f / (1.f + __expf(-v));
                    const int node = node_base + r;
                    const size_t idx = ((size_t)(b << 10) + node) * 64 + jc;
                    float zh = g * b2f(Hb[idx]);
                    unsigned short zb = f2b(zh);
                    Zb[idx] = zb;
                    pack[r] = zb;
                }
                *(u16x4*)&ZhT[(size_t)((b << 6) + jc) * 1024 + node_base] = pack;
            } else {
                for (int r = 0; r < 4; ++r) {
                    float v = acc2[i][j][r] + bj + c0[r] * w0 + c1[r] * w1 + c2[r] * w2
                              + c3[r] * w3 + c4[r] * w4 + c5[r] * w5;
                    float g = 1.f / (1.f + __expf(-v));
                    const int node = node_base + r;
                    R[((size_t)(b << 10) + node) * 64 + (jc - 64)] = f2b(g);
                }
            }
        }
    }
}

// ---------------------------------------------------------------------------
// cell_update: grid 512 = (b, n0-tile), 256 threads. Same LDS union.
// ---------------------------------------------------------------------------
__global__ __launch_bounds__(256, 4) void cell_update(
    const unsigned short* __restrict__ AA, const unsigned short* __restrict__ ZhT,
    const unsigned short* __restrict__ Zb, const unsigned short* __restrict__ WT,
    const float* __restrict__ bias, const float* __restrict__ wx,
    const float* __restrict__ xin, int t,
    const unsigned short* __restrict__ XSgT, int xsrow,
    const float* __restrict__ Sgo, const unsigned short* __restrict__ Rg,
    unsigned short* __restrict__ Hb, unsigned short* __restrict__ XhT,
    const float* __restrict__ prW, const float* __restrict__ prb,
    unsigned short* __restrict__ Go, float* __restrict__ outp, int dec)
{
    __shared__ __align__(16) unsigned char smem[36864];
    unsigned short* As  = (unsigned short*)smem;            // 256*32
    unsigned short* Bs  = (unsigned short*)(smem + 16384);  // 64*32
    unsigned short* Shs = (unsigned short*)smem;            // 256*72
    const int tid = threadIdx.x;
    const int b = blockIdx.x >> 3, n0 = (blockIdx.x & 7) << 7;
    const int w = tid >> 6, l = tid & 63;
    const int lr = l & 15, lq = l >> 4;
    const int arow = tid >> 2, ak = (tid & 3) << 3;

    // ---- Phase 1: Sz[256][64] = AA @ ZhT[b-rows]^T ----
    {
        const int wm = w << 6;
        f32x4 acc[4][4] = {};
        for (int k0 = 0; k0 < 1024; k0 += 32) {
#pragma unroll
            for (int p = 0; p < 4; ++p) {
                const int row = arow + (p << 6);
                const int grow = (p < 2) ? (n0 + row) : (896 + n0 + row);
                GLOAD_LDS16(AA + (size_t)grow * 1024 + k0 + ak, &As[(row << 5) + ak]);
            }
            GLOAD_LDS16(ZhT + (size_t)((b << 6) + arow) * 1024 + k0 + ak,
                        &Bs[(arow << 5) + ak]);
            __syncthreads();
            bf16x8 a[4], bb[4];
#pragma unroll
            for (int i = 0; i < 4; ++i)
                a[i] = *(const bf16x8*)&As[((wm + (i << 4) + lr) << 5) + (lq << 3)];
#pragma unroll
            for (int j = 0; j < 4; ++j)
                bb[j] = *(const bf16x8*)&Bs[(((j << 4) + lr) << 5) + (lq << 3)];
#pragma unroll
            for (int i = 0; i < 4; ++i)
#pragma unroll
                for (int j = 0; j < 4; ++j)
                    acc[i][j] = __builtin_amdgcn_mfma_f32_16x16x32_bf16(a[i], bb[j], acc[i][j], 0, 0, 0);
            __syncthreads();
        }
#pragma unroll
        for (int i = 0; i < 4; ++i)
#pragma unroll
            for (int j = 0; j < 4; ++j)
#pragma unroll
                for (int r = 0; r < 4; ++r) {
                    const int m = wm + (i << 4) + (lq << 2) + r;
                    const int c = (j << 4) + lr;
                    Shs[m * 72 + c] = f2b(acc[i][j][r]);
                }
    }
    __syncthreads();

    // ---- Phase 2: hc = tanh([zh | Sz_A | Sz_2A2] @ Wu + bias + corr) ----
    const int wm2 = w << 5;
    f32x4 acc2[2][4] = {};
    for (int kk0 = 0; kk0 < 192; kk0 += 32) {
        bf16x8 a[2], bb[4];
        if (kk0 < 64) {
#pragma unroll
            for (int i = 0; i < 2; ++i)
                a[i] = *(const bf16x8*)(Zb + ((size_t)(b << 10) + n0 + wm2 + (i << 4) + lr) * 64 + kk0 + (lq << 3));
        } else {
            const int rowb = (kk0 >= 128) ? 128 : 0;
            const int c0 = kk0 & 63;
#pragma unroll
            for (int i = 0; i < 2; ++i)
                a[i] = *(const bf16x8*)&Shs[(rowb + wm2 + (i << 4) + lr) * 72 + c0 + (lq << 3)];
        }
#pragma unroll
        for (int j = 0; j < 4; ++j)
            bb[j] = *(const bf16x8*)(WT + (size_t)((j << 4) + lr) * 192 + kk0 + (lq << 3));
#pragma unroll
        for (int i = 0; i < 2; ++i)
#pragma unroll
            for (int j = 0; j < 4; ++j)
                acc2[i][j] = __builtin_amdgcn_mfma_f32_16x16x32_bf16(a[i], bb[j], acc2[i][j], 0, 0, 0);
    }

    float pw[4];
    if (dec) {
#pragma unroll
        for (int j = 0; j < 4; ++j) pw[j] = prW[(j << 4) + lr];
    }

#pragma unroll
    for (int i = 0; i < 2; ++i) {
        const int node_base = n0 + wm2 + (i << 4) + (lq << 2);
        float c0[4], c1[4], c2[4], c3[4], c4[4], c5[4];
        for (int r = 0; r < 4; ++r) {
            const int node = node_base + r;
            if (!dec) {
                c0[r] = xin[((b * 12 + t) << 10) + node];
                c1[r] = b2f(XSgT[(size_t)(xsrow + t * 64 + b) * 2048 + node]);
                c2[r] = b2f(XSgT[(size_t)(xsrow + t * 64 + b) * 2048 + 1024 + node]);
                c3[r] = c4[r] = c5[r] = 0.f;
            } else {
                c0[r] = b2f(Go[(b << 10) + node]);
                c1[r] = xin[((b * 12 + t) << 10) + node];
                c2[r] = Sgo[(size_t)node * 64 + b];
                c3[r] = b2f(XSgT[(size_t)(xsrow + t * 64 + b) * 2048 + node]);
                c4[r] = Sgo[(size_t)(1024 + node) * 64 + b];
                c5[r] = b2f(XSgT[(size_t)(xsrow + t * 64 + b) * 2048 + 1024 + node]);
            }
        }
        float psum[4] = {0.f, 0.f, 0.f, 0.f};
#pragma unroll
        for (int j = 0; j < 4; ++j) {
            const int jc = (j << 4) + lr;
            const float bj = bias[jc];
            const float w0 = wx[jc], w1 = wx[64 + jc], w2 = wx[128 + jc];
            float w3 = 0.f, w4 = 0.f, w5 = 0.f;
            if (dec) { w3 = wx[192 + jc]; w4 = wx[256 + jc]; w5 = wx[320 + jc]; }
            u16x4 pack;
            for (int r = 0; r < 4; ++r) {
                float v = acc2[i][j][r] + bj + c0[r] * w0 + c1[r] * w1 + c2[r] * w2
                          + c3[r] * w3 + c4[r] * w4 + c5[r] * w5;
                float hc = tanhf(v);
                const int node = node_base + r;
                const size_t idx = ((size_t)(b << 10) + node) * 64 + jc;
                float rr = b2f(Rg[idx]);
                float hn = rr * b2f(Hb[idx]) + (1.f - rr) * hc;
                unsigned short hb = f2b(hn);
                Hb[idx] = hb;
                pack[r] = hb;
                if (dec) psum[r] += hn * pw[j];
            }
            *(u16x4*)&XhT[(size_t)((b << 6) + jc) * 1024 + node_base] = pack;
        }
        if (dec) {
#pragma unroll
            for (int r = 0; r < 4; ++r) {
                float v = psum[r];
                v += __shfl_down(v, 8, 16);
                v += __shfl_down(v, 4, 16);
                v += __shfl_down(v, 2, 16);
                v += __shfl_down(v, 1, 16);
                if (lr == 0) {
                    const int node = node_base + r;
                    const float go = v + prb[0];
                    Go[(b << 10) + node] = f2b(go);
                    outp[((size_t)(b * 12 + t) << 10) + node] = go;
                }
            }
        }
    }
}

// ---------------------------------------------------------------------------
__global__ __launch_bounds__(256) void adj_softmax(
    const float* __restrict__ E, unsigned short* __restrict__ A)
{
    __shared__ float Es[8192];
    __shared__ float vals[1024];
    __shared__ float red[8];
    const int tid = threadIdx.x;
    const int r = blockIdx.x;
    for (int i = tid; i < 8192; i += 256) Es[i] = E[i];
    __syncthreads();
    float er[8];
#pragma unroll
    for (int e = 0; e < 8; ++e) er[e] = Es[(r << 3) + e];
    float lmax = -1e30f;
    for (int c = tid; c < 1024; c += 256) {
        float s = 0.f;
#pragma unroll
        for (int e = 0; e < 8; ++e) s += er[e] * Es[(c << 3) + e];
        s = fmaxf(s, 0.f);
        vals[c] = s;
        lmax = fmaxf(lmax, s);
    }
    for (int off = 32; off; off >>= 1) lmax = fmaxf(lmax, __shfl_down(lmax, off, 64));
    if ((tid & 63) == 0) red[tid >> 6] = lmax;
    __syncthreads();
    const float m = fmaxf(fmaxf(red[0], red[1]), fmaxf(red[2], red[3]));
    float lsum = 0.f;
    for (int c = tid; c < 1024; c += 256) {
        float e = __expf(vals[c] - m);
        vals[c] = e;
        lsum += e;
    }
    for (int off = 32; off; off >>= 1) lsum += __shfl_down(lsum, off, 64);
    if ((tid & 63) == 0) red[4 + (tid >> 6)] = lsum;
    __syncthreads();
    const float inv = 1.f / (red[4] + red[5] + red[6] + red[7]);
    for (int c = tid; c < 1024; c += 256)
        A[(r << 10) + c] = f2b(vals[c] * inv);
}

__global__ __launch_bounds__(256) void transpose_bf16(
    const unsigned short* __restrict__ src, unsigned short* __restrict__ dst)
{
    __shared__ unsigned short tile[64][65];
    const int bx = blockIdx.x & 15, by = blockIdx.x >> 4;
    const int x0 = bx << 6, y0 = by << 6;
    for (int i = threadIdx.x; i < 4096; i += 256) {
        const int r = i >> 6, c = i & 63;
        tile[r][c] = src[((y0 + r) << 10) + x0 + c];
    }
    __syncthreads();
    for (int i = threadIdx.x; i < 4096; i += 256) {
        const int r = i >> 6, c = i & 63;
        dst[((x0 + r) << 10) + y0 + c] = tile[c][r];
    }
}

__global__ __launch_bounds__(256) void build_xall(
    const float* __restrict__ x, const float* __restrict__ y,
    unsigned short* __restrict__ XallT)
{
    const int id = blockIdx.x * 256 + threadIdx.x;
    const int row = id >> 10, n = id & 1023;
    int t, b;
    const float* src;
    if (row < 768) { t = row >> 6; b = row & 63; src = x; }
    else { const int rr = row - 768; t = rr >> 6; b = rr & 63; src = y; }
    XallT[id] = f2b(src[((b * 12 + t) << 10) + n]);
}

__global__ __launch_bounds__(256) void wprep(
    const float* egW, const float* egb,
    const float* euW, const float* eub,
    const float* dgW, const float* dgb,
    const float* duW, const float* dub,
    const float* pW, const float* pb,
    unsigned short* WgTe, unsigned short* WuTe, unsigned short* WgTd, unsigned short* WuTd,
    float* wxge, float* wxue, float* wxgd, float* wxud,
    float* bge, float* bue, float* bgd, float* bud,
    float* projW, float* projb)
{
    const int tid0 = blockIdx.x * 256 + threadIdx.x;
    const int stride = 256 * gridDim.x;
    for (int i = tid0; i < 128 * 192; i += stride) {
        const int j = i / 192, kk = i % 192, k = kk >> 6, c = kk & 63;
        float v = egW[(k * 65 + 1 + c) * 128 + j];
        if (k == 0) v -= egW[(131 + c) * 128 + j];
        WgTe[i] = f2b(v);
    }
    for (int i = tid0; i < 64 * 192; i += stride) {
        const int j = i / 192, kk = i % 192, k = kk >> 6, c = kk & 63;
        float v = euW[(k * 65 + 1 + c) * 64 + j];
        if (k == 0) v -= euW[(131 + c) * 64 + j];
        WuTe[i] = f2b(v);
    }
    for (int i = tid0; i < 128 * 192; i += stride) {
        const int j = i / 192, kk = i % 192, k = kk >> 6, c = kk & 63;
        float v = dgW[(k * 66 + 2 + c) * 128 + j];
        if (k == 0) v -= dgW[(134 + c) * 128 + j];
        WgTd[i] = f2b(v);
    }
    for (int i = tid0; i < 64 * 192; i += stride) {
        const int j = i / 192, kk = i % 192, k = kk >> 6, c = kk & 63;
        float v = duW[(k * 66 + 2 + c) * 64 + j];
        if (k == 0) v -= duW[(134 + c) * 64 + j];
        WuTd[i] = f2b(v);
    }
    for (int i = tid0; i < 384; i += stride) {
        const int k = i >> 7, j = i & 127;
        float v;
        if (k == 0) v = egW[j] - egW[130 * 128 + j];
        else if (k == 1) v = egW[65 * 128 + j];
        else v = egW[130 * 128 + j];
        wxge[i] = v;
    }
    for (int i = tid0; i < 192; i += stride) {
        const int k = i >> 6, j = i & 63;
        float v;
        if (k == 0) v = euW[j] - euW[130 * 64 + j];
        else if (k == 1) v = euW[65 * 64 + j];
        else v = euW[130 * 64 + j];
        wxue[i] = v;
    }
    for (int i = tid0; i < 768; i += stride) {
        const int k = i >> 7, j = i & 127;
        float v;
        switch (k) {
            case 0: v = dgW[j] - dgW[132 * 128 + j]; break;
            case 1: v = dgW[128 + j] - dgW[133 * 128 + j]; break;
            case 2: v = dgW[66 * 128 + j]; break;
            case 3: v = dgW[67 * 128 + j]; break;
            case 4: v = dgW[132 * 128 + j]; break;
            default: v = dgW[133 * 128 + j]; break;
        }
        wxgd[i] = v;
    }
    for (int i = tid0; i < 384; i += stride) {
        const int k = i >> 6, j = i & 63;
        float v;
        switch (k) {
            case 0: v = duW[j] - duW[132 * 64 + j]; break;
            case 1: v = duW[64 + j] - duW[133 * 64 + j]; break;
            case 2: v = duW[66 * 64 + j]; break;
            case 3: v = duW[67 * 64 + j]; break;
            case 4: v = duW[132 * 64 + j]; break;
            default: v = duW[133 * 64 + j]; break;
        }
        wxud[i] = v;
    }
    for (int i = tid0; i < 128; i += stride) bge[i] = egb[i];
    for (int i = tid0; i < 64; i += stride) bue[i] = eub[i];
    for (int i = tid0; i < 128; i += stride) bgd[i] = dgb[i];
    for (int i = tid0; i < 64; i += stride) bud[i] = dub[i];
    for (int i = tid0; i < 64; i += stride) projW[i] = pW[i];
    if (tid0 == 0) projb[0] = pb[0];
}

// ---------------------------------------------------------------------------
extern "C" void kernel_launch(void* const* d_in, const int* in_sizes, int n_in,
                              void* d_out, int out_size, void* d_ws, size_t ws_size,
                              hipStream_t stream)
{
    (void)in_sizes; (void)n_in; (void)out_size; (void)ws_size;
    const float* x    = (const float*)d_in[0];
    const float* ycov = (const float*)d_in[1];
    const float* E    = (const float*)d_in[2];
    const float* egW  = (const float*)d_in[3];
    const float* egb  = (const float*)d_in[4];
    const float* euW  = (const float*)d_in[5];
    const float* eub  = (const float*)d_in[6];
    const float* dgW  = (const float*)d_in[7];
    const float* dgb  = (const float*)d_in[8];
    const float* duW  = (const float*)d_in[9];
    const float* dub  = (const float*)d_in[10];
    const float* pW   = (const float*)d_in[11];
    const float* pb   = (const float*)d_in[12];
    float* out = (float*)d_out;

    size_t off = 0;
    auto carve = [&](size_t bytes) -> void* {
        void* p = (char*)d_ws + off;
        off += (bytes + 255) & ~(size_t)255;
        return p;
    };
    unsigned short* AA    = (unsigned short*)carve(2048ull * 1024 * 2); // [A; 2A^2]
    unsigned short* XSgT  = (unsigned short*)carve(1536ull * 2048 * 2);
    unsigned short* XhT   = (unsigned short*)carve(4096ull * 1024 * 2);
    unsigned short* ZhT   = (unsigned short*)carve(4096ull * 1024 * 2);
    unsigned short* Hb    = (unsigned short*)carve(65536ull * 64 * 2);
    unsigned short* Zb    = (unsigned short*)carve(65536ull * 64 * 2);
    unsigned short* R     = (unsigned short*)carve(65536ull * 64 * 2);
    float*          Sgo   = (float*)carve(2048ull * 64 * 4);
    unsigned short* Go    = (unsigned short*)carve(65536ull * 2);
    unsigned short* WgTe  = (unsigned short*)carve(128ull * 192 * 2);
    unsigned short* WuTe  = (unsigned short*)carve(64ull * 192 * 2);
    unsigned short* WgTd  = (unsigned short*)carve(128ull * 192 * 2);
    unsigned short* WuTd  = (unsigned short*)carve(64ull * 192 * 2);
    float* wxge = (float*)carve(384 * 4);
    float* wxue = (float*)carve(192 * 4);
    float* wxgd = (float*)carve(768 * 4);
    float* wxud = (float*)carve(384 * 4);
    float* bge  = (float*)carve(128 * 4);
    float* bue  = (float*)carve(64 * 4);
    float* bgd  = (float*)carve(128 * 4);
    float* bud  = (float*)carve(64 * 4);
    float* prW  = (float*)carve(64 * 4);
    float* prb  = (float*)carve(4);
    // Aliases: AT and XallT live inside Zb (both consumed before Zb's first write).
    unsigned short* AT    = Zb;
    unsigned short* XallT = Zb + 1024ull * 1024;

    hipMemsetAsync(XhT, 0, 4096ull * 1024 * 2, stream);
    hipMemsetAsync(Hb, 0, 65536ull * 64 * 2, stream);
    hipMemsetAsync(Go, 0, 65536ull * 2, stream);

    adj_softmax<<<1024, 256, 0, stream>>>(E, AA);
    transpose_bf16<<<256, 256, 0, stream>>>(AA, AT);
    gemm_bt<<<dim3(8, 8), 256, 0, stream>>>(AA, 1024, AT, 1024, AA + 1024 * 1024, 1024, 1024, 2.0f);
    build_xall<<<6144, 256, 0, stream>>>(x, ycov, XallT);
    gemm_bt<<<dim3(16, 12), 256, 0, stream>>>(XallT, 1024, AA, 1024, XSgT, 2048, 1024, 1.0f);
    wprep<<<64, 256, 0, stream>>>(egW, egb, euW, eub, dgW, dgb, duW, dub, pW, pb,
                                  WgTe, WuTe, WgTd, WuTd, wxge, wxue, wxgd, wxud,
                                  bge, bue, bgd, bud, prW, prb);

    for (int t = 0; t < 12; ++t) {  // encoder
        cell_gate<<<512, 256, 0, stream>>>(AA, XhT, Hb, WgTe, bge, wxge, x, t, XSgT, 0,
                                           Go, prW, prb, Sgo, Zb, ZhT, R, 0, 0);
        cell_update<<<512, 256, 0, stream>>>(AA, ZhT, Zb, WuTe, bue, wxue, x, t, XSgT, 0,
                                             Sgo, R, Hb, XhT, prW, prb, Go, out, 0);
    }
    for (int t = 0; t < 12; ++t) {  // decoder
        cell_gate<<<512, 256, 0, stream>>>(AA, XhT, Hb, WgTd, bgd, wxgd, ycov, t, XSgT, 768,
                                           Go, prW, prb, Sgo, Zb, ZhT, R, 1, t > 0 ? 1 : 0);
        cell_update<<<512, 256, 0, stream>>>(AA, ZhT, Zb, WuTd, bud, wxud, ycov, t, XSgT, 768,
                                             Sgo, R, Hb, XhT, prW, prb, Go, out, 1);
    }
}

// Round 10
// 2523.373 us; speedup vs baseline: 1.6169x; 1.0021x over previous
//
#include <hip/hip_runtime.h>

// GCRN (AGCRN-style) on gfx950. Inputs/outputs fp32; internal compute bf16 MFMA.
// A = softmax(relu(E E^T)); AA = [A; 2A^2] stacked (T2 = 2A^2 - I folded into
// weights: W0' = W0 - W2).
// Round 10: R9 base minus the VGPR clamp (launch_bounds(256) plain — the ,4
// clamp forced VGPR 64 and cost scheduling depth), plus n0-major grid swizzle
// (XCD L2 keeps XhT b-slices resident; AA streams once), plus phase-2 global
// fragment loads (Hb/Zb) hoisted above the Shs-publish barrier.

typedef __attribute__((ext_vector_type(8))) short bf16x8;
typedef __attribute__((ext_vector_type(4))) float f32x4;
typedef __attribute__((ext_vector_type(4))) unsigned short u16x4;

__device__ __forceinline__ float b2f(unsigned short u) {
    union { unsigned int i; float f; } v; v.i = ((unsigned int)u) << 16; return v.f;
}
__device__ __forceinline__ unsigned short f2b(float f) {
    union { float f; unsigned int i; } v; v.f = f;
    unsigned int r = v.i + 0x7FFFu + ((v.i >> 16) & 1u);
    return (unsigned short)(r >> 16);
}

// LDS dest is wave-uniform base + lane*16 (m104/m108 rule).
#define GLOAD_LDS16(g, l) __builtin_amdgcn_global_load_lds( \
    (const __attribute__((address_space(1))) void*)(g),     \
    (__attribute__((address_space(3))) void*)(l), 16, 0, 0)

// ---------------------------------------------------------------------------
// Generic bf16 GEMM (preamble only): C[m,n] = scale * sum_k P[m,k]*QT[n,k].
// ---------------------------------------------------------------------------
__global__ __launch_bounds__(256) void gemm_bt(
    const unsigned short* __restrict__ P, int lda,
    const unsigned short* __restrict__ QT, int ldb,
    unsigned short* __restrict__ C, int ldc,
    int K, float scale)
{
    __shared__ __align__(16) unsigned short As[128 * 32];
    __shared__ __align__(16) unsigned short Bs[128 * 32];
    const int tid = threadIdx.x;
    const int m0 = blockIdx.y << 7, n0 = blockIdx.x << 7;
    const int w = tid >> 6, l = tid & 63;
    const int wm = (w >> 1) << 6, wn = (w & 1) << 6;
    const int lr = l & 15, lq = l >> 4;
    const int arow = tid >> 2, ak = (tid & 3) << 3;
    f32x4 acc[4][4] = {};

    for (int k0 = 0; k0 < K; k0 += 32) {
#pragma unroll
        for (int p = 0; p < 2; ++p)
            GLOAD_LDS16(P + (size_t)(m0 + arow + (p << 6)) * lda + k0 + ak,
                        &As[((arow + (p << 6)) << 5) + ak]);
#pragma unroll
        for (int p = 0; p < 2; ++p)
            GLOAD_LDS16(QT + (size_t)(n0 + arow + (p << 6)) * ldb + k0 + ak,
                        &Bs[((arow + (p << 6)) << 5) + ak]);
        __syncthreads();
        bf16x8 a[4], b[4];
#pragma unroll
        for (int i = 0; i < 4; ++i)
            a[i] = *(const bf16x8*)&As[((wm + (i << 4) + lr) << 5) + (lq << 3)];
#pragma unroll
        for (int j = 0; j < 4; ++j)
            b[j] = *(const bf16x8*)&Bs[((wn + (j << 4) + lr) << 5) + (lq << 3)];
#pragma unroll
        for (int i = 0; i < 4; ++i)
#pragma unroll
            for (int j = 0; j < 4; ++j)
                acc[i][j] = __builtin_amdgcn_mfma_f32_16x16x32_bf16(a[i], b[j], acc[i][j], 0, 0, 0);
        __syncthreads();
    }
#pragma unroll
    for (int i = 0; i < 4; ++i)
#pragma unroll
        for (int j = 0; j < 4; ++j)
#pragma unroll
            for (int r = 0; r < 4; ++r) {
                const int m = m0 + wm + (i << 4) + (lq << 2) + r;
                const int n = n0 + wn + (j << 4) + lr;
                C[(size_t)m * ldc + n] = f2b(acc[i][j][r] * scale);
            }
}

// ---------------------------------------------------------------------------
// cell_gate: grid 512 = (n0-tile major) x (b minor), 256 threads.
// LDS union: [phase1: As 256x32 | Bs 64x32] aliased with [Shs 256x72 | SgoS].
// ---------------------------------------------------------------------------
__global__ __launch_bounds__(256) void cell_gate(
    const unsigned short* __restrict__ AA, const unsigned short* __restrict__ XhT,
    const unsigned short* __restrict__ Hb, const unsigned short* __restrict__ WT,
    const float* __restrict__ bias, const float* __restrict__ wx,
    const float* __restrict__ xin, int t,
    const unsigned short* __restrict__ XSgT, int xsrow,
    const unsigned short* __restrict__ Go,
    const float* __restrict__ prW, const float* __restrict__ prb,
    float* __restrict__ Sgo,
    unsigned short* __restrict__ Zb, unsigned short* __restrict__ ZhT,
    unsigned short* __restrict__ R, int dec, int goflag)
{
    __shared__ __align__(16) unsigned char smem[37888];
    unsigned short* As  = (unsigned short*)smem;            // 256*32 = 16 KB
    unsigned short* Bs  = (unsigned short*)(smem + 16384);  // 64*32  =  4 KB
    unsigned short* Shs = (unsigned short*)smem;            // 256*72 = 36 KB
    float* SgoS = (float*)(smem + 36864);                   // 256 floats
    const int tid = threadIdx.x;
    // n0-major: 64 consecutive blocks share the same AA slice (XCD L2 locality)
    const int b = blockIdx.x & 63, n0 = (blockIdx.x >> 6) << 7;
    const int w = tid >> 6, l = tid & 63;
    const int lr = l & 15, lq = l >> 4;
    const int arow = tid >> 2, ak = (tid & 3) << 3;

    // ---- Phase 1: Sh[256][64] = AA[{n0..n0+127, 1024+n0..}] @ XhT[b-rows]^T
    {
        const int wm = w << 6;   // wave M base: 0,64,128,192
        f32x4 acc[4][4] = {};
        for (int k0 = 0; k0 < 1024; k0 += 32) {
#pragma unroll
            for (int p = 0; p < 4; ++p) {
                const int row = arow + (p << 6);
                const int grow = (p < 2) ? (n0 + row) : (896 + n0 + row);
                GLOAD_LDS16(AA + (size_t)grow * 1024 + k0 + ak, &As[(row << 5) + ak]);
            }
            GLOAD_LDS16(XhT + (size_t)((b << 6) + arow) * 1024 + k0 + ak,
                        &Bs[(arow << 5) + ak]);
            __syncthreads();
            bf16x8 a[4], bb[4];
#pragma unroll
            for (int i = 0; i < 4; ++i)
                a[i] = *(const bf16x8*)&As[((wm + (i << 4) + lr) << 5) + (lq << 3)];
#pragma unroll
            for (int j = 0; j < 4; ++j)
                bb[j] = *(const bf16x8*)&Bs[(((j << 4) + lr) << 5) + (lq << 3)];
#pragma unroll
            for (int i = 0; i < 4; ++i)
#pragma unroll
                for (int j = 0; j < 4; ++j)
                    acc[i][j] = __builtin_amdgcn_mfma_f32_16x16x32_bf16(a[i], bb[j], acc[i][j], 0, 0, 0);
            __syncthreads();   // all LDS reads done -> safe to alias As/Bs below
        }
        // Sh -> LDS (bf16), overwriting the staging region (lifetimes disjoint)
#pragma unroll
        for (int i = 0; i < 4; ++i)
#pragma unroll
            for (int j = 0; j < 4; ++j)
#pragma unroll
                for (int r = 0; r < 4; ++r) {
                    const int m = wm + (i << 4) + (lq << 2) + r;
                    const int c = (j << 4) + lr;
                    Shs[m * 72 + c] = f2b(acc[i][j][r]);
                }
        if (dec) {
            float pw[4];
#pragma unroll
            for (int j = 0; j < 4; ++j) pw[j] = prW[(j << 4) + lr];
            const float pb0 = prb[0];
#pragma unroll
            for (int i = 0; i < 4; ++i)
#pragma unroll
                for (int r = 0; r < 4; ++r) {
                    float v = acc[i][0][r] * pw[0] + acc[i][1][r] * pw[1]
                            + acc[i][2][r] * pw[2] + acc[i][3][r] * pw[3];
                    v += __shfl_down(v, 8, 16);
                    v += __shfl_down(v, 4, 16);
                    v += __shfl_down(v, 2, 16);
                    v += __shfl_down(v, 1, 16);
                    if (lr == 0) {
                        const int m = wm + (i << 4) + (lq << 2) + r;
                        const int grow = (m < 128) ? (n0 + m) : (896 + n0 + m);
                        // t=0: GO token is zero -> A@go = 0 (goflag==0)
                        const float val = goflag
                            ? (v + pb0 * ((m < 128) ? 1.f : 2.f)) : 0.f;
                        Sgo[(size_t)grow * 64 + b] = val;
                        SgoS[m] = val;
                    }
                }
        }
    }

    // Hoist phase-2 Hb fragments (independent of Shs) above the publish barrier:
    // their latency overlaps the barrier drain.
    const int wm2 = (w >> 1) << 6, wn2 = (w & 1) << 6;
    bf16x8 hfa[2][4];
#pragma unroll
    for (int kq = 0; kq < 2; ++kq)
#pragma unroll
        for (int i = 0; i < 4; ++i)
            hfa[kq][i] = *(const bf16x8*)(Hb + ((size_t)(b << 10) + n0 + wm2 + (i << 4) + lr) * 64 + (kq << 5) + (lq << 3));

    __syncthreads();   // Shs/SgoS ready for all waves

    // ---- Phase 2: zr = sigmoid([h | Sh_A | Sh_2A2] @ W + bias + corr) ----
    f32x4 acc2[4][4] = {};
    for (int kk0 = 0; kk0 < 192; kk0 += 32) {
        bf16x8 a[4], bb[4];
        if (kk0 < 64) {
#pragma unroll
            for (int i = 0; i < 4; ++i)
                a[i] = hfa[kk0 >> 5][i];
        } else {
            const int rowb = (kk0 >= 128) ? 128 : 0;
            const int c0 = kk0 & 63;
#pragma unroll
            for (int i = 0; i < 4; ++i)
                a[i] = *(const bf16x8*)&Shs[(rowb + wm2 + (i << 4) + lr) * 72 + c0 + (lq << 3)];
        }
#pragma unroll
        for (int j = 0; j < 4; ++j)
            bb[j] = *(const bf16x8*)(WT + (size_t)(wn2 + (j << 4) + lr) * 192 + kk0 + (lq << 3));
#pragma unroll
        for (int i = 0; i < 4; ++i)
#pragma unroll
            for (int j = 0; j < 4; ++j)
                acc2[i][j] = __builtin_amdgcn_mfma_f32_16x16x32_bf16(a[i], bb[j], acc2[i][j], 0, 0, 0);
    }

#pragma unroll
    for (int i = 0; i < 4; ++i) {
        const int nb_loc = wm2 + (i << 4) + (lq << 2);      // local node 0..127
        const int node_base = n0 + nb_loc;
        float c0[4], c1[4], c2[4], c3[4], c4[4], c5[4];
        for (int r = 0; r < 4; ++r) {
            const int node = node_base + r;
            if (!dec) {
                c0[r] = xin[((b * 12 + t) << 10) + node];
                c1[r] = b2f(XSgT[(size_t)(xsrow + t * 64 + b) * 2048 + node]);
                c2[r] = b2f(XSgT[(size_t)(xsrow + t * 64 + b) * 2048 + 1024 + node]);
                c3[r] = c4[r] = c5[r] = 0.f;
            } else {
                c0[r] = b2f(Go[(b << 10) + node]);
                c1[r] = xin[((b * 12 + t) << 10) + node];
                c2[r] = SgoS[nb_loc + r];
                c3[r] = b2f(XSgT[(size_t)(xsrow + t * 64 + b) * 2048 + node]);
                c4[r] = SgoS[128 + nb_loc + r];
                c5[r] = b2f(XSgT[(size_t)(xsrow + t * 64 + b) * 2048 + 1024 + node]);
            }
        }
#pragma unroll
        for (int j = 0; j < 4; ++j) {
            const int jc = wn2 + (j << 4) + lr;
            const float bj = bias[jc];
            const float w0 = wx[jc], w1 = wx[128 + jc], w2 = wx[256 + jc];
            float w3 = 0.f, w4 = 0.f, w5 = 0.f;
            if (dec) { w3 = wx[384 + jc]; w4 = wx[512 + jc]; w5 = wx[640 + jc]; }
            if (jc < 64) {
                u16x4 pack;
                for (int r = 0; r < 4; ++r) {
                    float v = acc2[i][j][r] + bj + c0[r] * w0 + c1[r] * w1 + c2[r] * w2
                              + c3[r] * w3 + c4[r] * w4 + c5[r] * w5;
                    float g = 1.f / (1.f + __expf(-v));
                    const int node = node_base + r;
                    const size_t idx = ((size_t)(b << 10) + node) * 64 + jc;
                    float zh = g * b2f(Hb[idx]);
                    unsigned short zb = f2b(zh);
                    Zb[idx] = zb;
                    pack[r] = zb;
                }
                *(u16x4*)&ZhT[(size_t)((b << 6) + jc) * 1024 + node_base] = pack;
            } else {
                for (int r = 0; r < 4; ++r) {
                    float v = acc2[i][j][r] + bj + c0[r] * w0 + c1[r] * w1 + c2[r] * w2
                              + c3[r] * w3 + c4[r] * w4 + c5[r] * w5;
                    float g = 1.f / (1.f + __expf(-v));
                    const int node = node_base + r;
                    R[((size_t)(b << 10) + node) * 64 + (jc - 64)] = f2b(g);
                }
            }
        }
    }
}

// ---------------------------------------------------------------------------
// cell_update: grid 512 = (n0-tile major) x (b minor), 256 threads.
// ---------------------------------------------------------------------------
__global__ __launch_bounds__(256) void cell_update(
    const unsigned short* __restrict__ AA, const unsigned short* __restrict__ ZhT,
    const unsigned short* __restrict__ Zb, const unsigned short* __restrict__ WT,
    const float* __restrict__ bias, const float* __restrict__ wx,
    const float* __restrict__ xin, int t,
    const unsigned short* __restrict__ XSgT, int xsrow,
    const float* __restrict__ Sgo, const unsigned short* __restrict__ Rg,
    unsigned short* __restrict__ Hb, unsigned short* __restrict__ XhT,
    const float* __restrict__ prW, const float* __restrict__ prb,
    unsigned short* __restrict__ Go, float* __restrict__ outp, int dec)
{
    __shared__ __align__(16) unsigned char smem[36864];
    unsigned short* As  = (unsigned short*)smem;            // 256*32
    unsigned short* Bs  = (unsigned short*)(smem + 16384);  // 64*32
    unsigned short* Shs = (unsigned short*)smem;            // 256*72
    const int tid = threadIdx.x;
    const int b = blockIdx.x & 63, n0 = (blockIdx.x >> 6) << 7;
    const int w = tid >> 6, l = tid & 63;
    const int lr = l & 15, lq = l >> 4;
    const int arow = tid >> 2, ak = (tid & 3) << 3;

    // ---- Phase 1: Sz[256][64] = AA @ ZhT[b-rows]^T ----
    {
        const int wm = w << 6;
        f32x4 acc[4][4] = {};
        for (int k0 = 0; k0 < 1024; k0 += 32) {
#pragma unroll
            for (int p = 0; p < 4; ++p) {
                const int row = arow + (p << 6);
                const int grow = (p < 2) ? (n0 + row) : (896 + n0 + row);
                GLOAD_LDS16(AA + (size_t)grow * 1024 + k0 + ak, &As[(row << 5) + ak]);
            }
            GLOAD_LDS16(ZhT + (size_t)((b << 6) + arow) * 1024 + k0 + ak,
                        &Bs[(arow << 5) + ak]);
            __syncthreads();
            bf16x8 a[4], bb[4];
#pragma unroll
            for (int i = 0; i < 4; ++i)
                a[i] = *(const bf16x8*)&As[((wm + (i << 4) + lr) << 5) + (lq << 3)];
#pragma unroll
            for (int j = 0; j < 4; ++j)
                bb[j] = *(const bf16x8*)&Bs[(((j << 4) + lr) << 5) + (lq << 3)];
#pragma unroll
            for (int i = 0; i < 4; ++i)
#pragma unroll
                for (int j = 0; j < 4; ++j)
                    acc[i][j] = __builtin_amdgcn_mfma_f32_16x16x32_bf16(a[i], bb[j], acc[i][j], 0, 0, 0);
            __syncthreads();
        }
#pragma unroll
        for (int i = 0; i < 4; ++i)
#pragma unroll
            for (int j = 0; j < 4; ++j)
#pragma unroll
                for (int r = 0; r < 4; ++r) {
                    const int m = wm + (i << 4) + (lq << 2) + r;
                    const int c = (j << 4) + lr;
                    Shs[m * 72 + c] = f2b(acc[i][j][r]);
                }
    }

    // Hoist phase-2 Zb fragments above the publish barrier.
    const int wm2 = w << 5;
    bf16x8 zfa[2][2];
#pragma unroll
    for (int kq = 0; kq < 2; ++kq)
#pragma unroll
        for (int i = 0; i < 2; ++i)
            zfa[kq][i] = *(const bf16x8*)(Zb + ((size_t)(b << 10) + n0 + wm2 + (i << 4) + lr) * 64 + (kq << 5) + (lq << 3));

    __syncthreads();

    // ---- Phase 2: hc = tanh([zh | Sz_A | Sz_2A2] @ Wu + bias + corr) ----
    f32x4 acc2[2][4] = {};
    for (int kk0 = 0; kk0 < 192; kk0 += 32) {
        bf16x8 a[2], bb[4];
        if (kk0 < 64) {
#pragma unroll
            for (int i = 0; i < 2; ++i)
                a[i] = zfa[kk0 >> 5][i];
        } else {
            const int rowb = (kk0 >= 128) ? 128 : 0;
            const int c0 = kk0 & 63;
#pragma unroll
            for (int i = 0; i < 2; ++i)
                a[i] = *(const bf16x8*)&Shs[(rowb + wm2 + (i << 4) + lr) * 72 + c0 + (lq << 3)];
        }
#pragma unroll
        for (int j = 0; j < 4; ++j)
            bb[j] = *(const bf16x8*)(WT + (size_t)((j << 4) + lr) * 192 + kk0 + (lq << 3));
#pragma unroll
        for (int i = 0; i < 2; ++i)
#pragma unroll
            for (int j = 0; j < 4; ++j)
                acc2[i][j] = __builtin_amdgcn_mfma_f32_16x16x32_bf16(a[i], bb[j], acc2[i][j], 0, 0, 0);
    }

    float pw[4];
    if (dec) {
#pragma unroll
        for (int j = 0; j < 4; ++j) pw[j] = prW[(j << 4) + lr];
    }

#pragma unroll
    for (int i = 0; i < 2; ++i) {
        const int node_base = n0 + wm2 + (i << 4) + (lq << 2);
        float c0[4], c1[4], c2[4], c3[4], c4[4], c5[4];
        for (int r = 0; r < 4; ++r) {
            const int node = node_base + r;
            if (!dec) {
                c0[r] = xin[((b * 12 + t) << 10) + node];
                c1[r] = b2f(XSgT[(size_t)(xsrow + t * 64 + b) * 2048 + node]);
                c2[r] = b2f(XSgT[(size_t)(xsrow + t * 64 + b) * 2048 + 1024 + node]);
                c3[r] = c4[r] = c5[r] = 0.f;
            } else {
                c0[r] = b2f(Go[(b << 10) + node]);
                c1[r] = xin[((b * 12 + t) << 10) + node];
                c2[r] = Sgo[(size_t)node * 64 + b];
                c3[r] = b2f(XSgT[(size_t)(xsrow + t * 64 + b) * 2048 + node]);
                c4[r] = Sgo[(size_t)(1024 + node) * 64 + b];
                c5[r] = b2f(XSgT[(size_t)(xsrow + t * 64 + b) * 2048 + 1024 + node]);
            }
        }
        float psum[4] = {0.f, 0.f, 0.f, 0.f};
#pragma unroll
        for (int j = 0; j < 4; ++j) {
            const int jc = (j << 4) + lr;
            const float bj = bias[jc];
            const float w0 = wx[jc], w1 = wx[64 + jc], w2 = wx[128 + jc];
            float w3 = 0.f, w4 = 0.f, w5 = 0.f;
            if (dec) { w3 = wx[192 + jc]; w4 = wx[256 + jc]; w5 = wx[320 + jc]; }
            u16x4 pack;
            for (int r = 0; r < 4; ++r) {
                float v = acc2[i][j][r] + bj + c0[r] * w0 + c1[r] * w1 + c2[r] * w2
                          + c3[r] * w3 + c4[r] * w4 + c5[r] * w5;
                float hc = tanhf(v);
                const int node = node_base + r;
                const size_t idx = ((size_t)(b << 10) + node) * 64 + jc;
                float rr = b2f(Rg[idx]);
                float hn = rr * b2f(Hb[idx]) + (1.f - rr) * hc;
                unsigned short hb = f2b(hn);
                Hb[idx] = hb;
                pack[r] = hb;
                if (dec) psum[r] += hn * pw[j];
            }
            *(u16x4*)&XhT[(size_t)((b << 6) + jc) * 1024 + node_base] = pack;
        }
        if (dec) {
#pragma unroll
            for (int r = 0; r < 4; ++r) {
                float v = psum[r];
                v += __shfl_down(v, 8, 16);
                v += __shfl_down(v, 4, 16);
                v += __shfl_down(v, 2, 16);
                v += __shfl_down(v, 1, 16);
                if (lr == 0) {
                    const int node = node_base + r;
                    const float go = v + prb[0];
                    Go[(b << 10) + node] = f2b(go);
                    outp[((size_t)(b * 12 + t) << 10) + node] = go;
                }
            }
        }
    }
}

// ---------------------------------------------------------------------------
__global__ __launch_bounds__(256) void adj_softmax(
    const float* __restrict__ E, unsigned short* __restrict__ A)
{
    __shared__ float Es[8192];
    __shared__ float vals[1024];
    __shared__ float red[8];
    const int tid = threadIdx.x;
    const int r = blockIdx.x;
    for (int i = tid; i < 8192; i += 256) Es[i] = E[i];
    __syncthreads();
    float er[8];
#pragma unroll
    for (int e = 0; e < 8; ++e) er[e] = Es[(r << 3) + e];
    float lmax = -1e30f;
    for (int c = tid; c < 1024; c += 256) {
        float s = 0.f;
#pragma unroll
        for (int e = 0; e < 8; ++e) s += er[e] * Es[(c << 3) + e];
        s = fmaxf(s, 0.f);
        vals[c] = s;
        lmax = fmaxf(lmax, s);
    }
    for (int off = 32; off; off >>= 1) lmax = fmaxf(lmax, __shfl_down(lmax, off, 64));
    if ((tid & 63) == 0) red[tid >> 6] = lmax;
    __syncthreads();
    const float m = fmaxf(fmaxf(red[0], red[1]), fmaxf(red[2], red[3]));
    float lsum = 0.f;
    for (int c = tid; c < 1024; c += 256) {
        float e = __expf(vals[c] - m);
        vals[c] = e;
        lsum += e;
    }
    for (int off = 32; off; off >>= 1) lsum += __shfl_down(lsum, off, 64);
    if ((tid & 63) == 0) red[4 + (tid >> 6)] = lsum;
    __syncthreads();
    const float inv = 1.f / (red[4] + red[5] + red[6] + red[7]);
    for (int c = tid; c < 1024; c += 256)
        A[(r << 10) + c] = f2b(vals[c] * inv);
}

__global__ __launch_bounds__(256) void transpose_bf16(
    const unsigned short* __restrict__ src, unsigned short* __restrict__ dst)
{
    __shared__ unsigned short tile[64][65];
    const int bx = blockIdx.x & 15, by = blockIdx.x >> 4;
    const int x0 = bx << 6, y0 = by << 6;
    for (int i = threadIdx.x; i < 4096; i += 256) {
        const int r = i >> 6, c = i & 63;
        tile[r][c] = src[((y0 + r) << 10) + x0 + c];
    }
    __syncthreads();
    for (int i = threadIdx.x; i < 4096; i += 256) {
        const int r = i >> 6, c = i & 63;
        dst[((x0 + r) << 10) + y0 + c] = tile[c][r];
    }
}

__global__ __launch_bounds__(256) void build_xall(
    const float* __restrict__ x, const float* __restrict__ y,
    unsigned short* __restrict__ XallT)
{
    const int id = blockIdx.x * 256 + threadIdx.x;
    const int row = id >> 10, n = id & 1023;
    int t, b;
    const float* src;
    if (row < 768) { t = row >> 6; b = row & 63; src = x; }
    else { const int rr = row - 768; t = rr >> 6; b = rr & 63; src = y; }
    XallT[id] = f2b(src[((b * 12 + t) << 10) + n]);
}

__global__ __launch_bounds__(256) void wprep(
    const float* egW, const float* egb,
    const float* euW, const float* eub,
    const float* dgW, const float* dgb,
    const float* duW, const float* dub,
    const float* pW, const float* pb,
    unsigned short* WgTe, unsigned short* WuTe, unsigned short* WgTd, unsigned short* WuTd,
    float* wxge, float* wxue, float* wxgd, float* wxud,
    float* bge, float* bue, float* bgd, float* bud,
    float* projW, float* projb)
{
    const int tid0 = blockIdx.x * 256 + threadIdx.x;
    const int stride = 256 * gridDim.x;
    for (int i = tid0; i < 128 * 192; i += stride) {
        const int j = i / 192, kk = i % 192, k = kk >> 6, c = kk & 63;
        float v = egW[(k * 65 + 1 + c) * 128 + j];
        if (k == 0) v -= egW[(131 + c) * 128 + j];
        WgTe[i] = f2b(v);
    }
    for (int i = tid0; i < 64 * 192; i += stride) {
        const int j = i / 192, kk = i % 192, k = kk >> 6, c = kk & 63;
        float v = euW[(k * 65 + 1 + c) * 64 + j];
        if (k == 0) v -= euW[(131 + c) * 64 + j];
        WuTe[i] = f2b(v);
    }
    for (int i = tid0; i < 128 * 192; i += stride) {
        const int j = i / 192, kk = i % 192, k = kk >> 6, c = kk & 63;
        float v = dgW[(k * 66 + 2 + c) * 128 + j];
        if (k == 0) v -= dgW[(134 + c) * 128 + j];
        WgTd[i] = f2b(v);
    }
    for (int i = tid0; i < 64 * 192; i += stride) {
        const int j = i / 192, kk = i % 192, k = kk >> 6, c = kk & 63;
        float v = duW[(k * 66 + 2 + c) * 64 + j];
        if (k == 0) v -= duW[(134 + c) * 64 + j];
        WuTd[i] = f2b(v);
    }
    for (int i = tid0; i < 384; i += stride) {
        const int k = i >> 7, j = i & 127;
        float v;
        if (k == 0) v = egW[j] - egW[130 * 128 + j];
        else if (k == 1) v = egW[65 * 128 + j];
        else v = egW[130 * 128 + j];
        wxge[i] = v;
    }
    for (int i = tid0; i < 192; i += stride) {
        const int k = i >> 6, j = i & 63;
        float v;
        if (k == 0) v = euW[j] - euW[130 * 64 + j];
        else if (k == 1) v = euW[65 * 64 + j];
        else v = euW[130 * 64 + j];
        wxue[i] = v;
    }
    for (int i = tid0; i < 768; i += stride) {
        const int k = i >> 7, j = i & 127;
        float v;
        switch (k) {
            case 0: v = dgW[j] - dgW[132 * 128 + j]; break;
            case 1: v = dgW[128 + j] - dgW[133 * 128 + j]; break;
            case 2: v = dgW[66 * 128 + j]; break;
            case 3: v = dgW[67 * 128 + j]; break;
            case 4: v = dgW[132 * 128 + j]; break;
            default: v = dgW[133 * 128 + j]; break;
        }
        wxgd[i] = v;
    }
    for (int i = tid0; i < 384; i += stride) {
        const int k = i >> 6, j = i & 63;
        float v;
        switch (k) {
            case 0: v = duW[j] - duW[132 * 64 + j]; break;
            case 1: v = duW[64 + j] - duW[133 * 64 + j]; break;
            case 2: v = duW[66 * 64 + j]; break;
            case 3: v = duW[67 * 64 + j]; break;
            case 4: v = duW[132 * 64 + j]; break;
            default: v = duW[133 * 64 + j]; break;
        }
        wxud[i] = v;
    }
    for (int i = tid0; i < 128; i += stride) bge[i] = egb[i];
    for (int i = tid0; i < 64; i += stride) bue[i] = eub[i];
    for (int i = tid0; i < 128; i += stride) bgd[i] = dgb[i];
    for (int i = tid0; i < 64; i += stride) bud[i] = dub[i];
    for (int i = tid0; i < 64; i += stride) projW[i] = pW[i];
    if (tid0 == 0) projb[0] = pb[0];
}

// ---------------------------------------------------------------------------
extern "C" void kernel_launch(void* const* d_in, const int* in_sizes, int n_in,
                              void* d_out, int out_size, void* d_ws, size_t ws_size,
                              hipStream_t stream)
{
    (void)in_sizes; (void)n_in; (void)out_size; (void)ws_size;
    const float* x    = (const float*)d_in[0];
    const float* ycov = (const float*)d_in[1];
    const float* E    = (const float*)d_in[2];
    const float* egW  = (const float*)d_in[3];
    const float* egb  = (const float*)d_in[4];
    const float* euW  = (const float*)d_in[5];
    const float* eub  = (const float*)d_in[6];
    const float* dgW  = (const float*)d_in[7];
    const float* dgb  = (const float*)d_in[8];
    const float* duW  = (const float*)d_in[9];
    const float* dub  = (const float*)d_in[10];
    const float* pW   = (const float*)d_in[11];
    const float* pb   = (const float*)d_in[12];
    float* out = (float*)d_out;

    size_t off = 0;
    auto carve = [&](size_t bytes) -> void* {
        void* p = (char*)d_ws + off;
        off += (bytes + 255) & ~(size_t)255;
        return p;
    };
    unsigned short* AA    = (unsigned short*)carve(2048ull * 1024 * 2); // [A; 2A^2]
    unsigned short* XSgT  = (unsigned short*)carve(1536ull * 2048 * 2);
    unsigned short* XhT   = (unsigned short*)carve(4096ull * 1024 * 2);
    unsigned short* ZhT   = (unsigned short*)carve(4096ull * 1024 * 2);
    unsigned short* Hb    = (unsigned short*)carve(65536ull * 64 * 2);
    unsigned short* Zb    = (unsigned short*)carve(65536ull * 64 * 2);
    unsigned short* R     = (unsigned short*)carve(65536ull * 64 * 2);
    float*          Sgo   = (float*)carve(2048ull * 64 * 4);
    unsigned short* Go    = (unsigned short*)carve(65536ull * 2);
    unsigned short* WgTe  = (unsigned short*)carve(128ull * 192 * 2);
    unsigned short* WuTe  = (unsigned short*)carve(64ull * 192 * 2);
    unsigned short* WgTd  = (unsigned short*)carve(128ull * 192 * 2);
    unsigned short* WuTd  = (unsigned short*)carve(64ull * 192 * 2);
    float* wxge = (float*)carve(384 * 4);
    float* wxue = (float*)carve(192 * 4);
    float* wxgd = (float*)carve(768 * 4);
    float* wxud = (float*)carve(384 * 4);
    float* bge  = (float*)carve(128 * 4);
    float* bue  = (float*)carve(64 * 4);
    float* bgd  = (float*)carve(128 * 4);
    float* bud  = (float*)carve(64 * 4);
    float* prW  = (float*)carve(64 * 4);
    float* prb  = (float*)carve(4);
    // Aliases: AT and XallT live inside Zb (both consumed before Zb's first write).
    unsigned short* AT    = Zb;
    unsigned short* XallT = Zb + 1024ull * 1024;

    hipMemsetAsync(XhT, 0, 4096ull * 1024 * 2, stream);
    hipMemsetAsync(Hb, 0, 65536ull * 64 * 2, stream);
    hipMemsetAsync(Go, 0, 65536ull * 2, stream);

    adj_softmax<<<1024, 256, 0, stream>>>(E, AA);
    transpose_bf16<<<256, 256, 0, stream>>>(AA, AT);
    gemm_bt<<<dim3(8, 8), 256, 0, stream>>>(AA, 1024, AT, 1024, AA + 1024 * 1024, 1024, 1024, 2.0f);
    build_xall<<<6144, 256, 0, stream>>>(x, ycov, XallT);
    gemm_bt<<<dim3(16, 12), 256, 0, stream>>>(XallT, 1024, AA, 1024, XSgT, 2048, 1024, 1.0f);
    wprep<<<64, 256, 0, stream>>>(egW, egb, euW, eub, dgW, dgb, duW, dub, pW, pb,
                                  WgTe, WuTe, WgTd, WuTd, wxge, wxue, wxgd, wxud,
                                  bge, bue, bgd, bud, prW, prb);

    for (int t = 0; t < 12; ++t) {  // encoder
        cell_gate<<<512, 256, 0, stream>>>(AA, XhT, Hb, WgTe, bge, wxge, x, t, XSgT, 0,
                                           Go, prW, prb, Sgo, Zb, ZhT, R, 0, 0);
        cell_update<<<512, 256, 0, stream>>>(AA, ZhT, Zb, WuTe, bue, wxue, x, t, XSgT, 0,
                                             Sgo, R, Hb, XhT, prW, prb, Go, out, 0);
    }
    for (int t = 0; t < 12; ++t) {  // decoder
        cell_gate<<<512, 256, 0, stream>>>(AA, XhT, Hb, WgTd, bgd, wxgd, ycov, t, XSgT, 768,
                                           Go, prW, prb, Sgo, Zb, ZhT, R, 1, t > 0 ? 1 : 0);
        cell_update<<<512, 256, 0, stream>>>(AA, ZhT, Zb, WuTd, bud, wxud, ycov, t, XSgT, 768,
                                             Sgo, R, Hb, XhT, prW, prb, Go, out, 1);
    }
}

// Round 11
// 2483.021 us; speedup vs baseline: 1.6432x; 1.0163x over previous
//
#include <hip/hip_runtime.h>

// GCRN (AGCRN-style) on gfx950. Inputs/outputs fp32; internal compute bf16 MFMA.
// A = softmax(relu(E E^T)); AA = [A; 2A^2] stacked (T2 = 2A^2 - I folded into
// weights: W0' = W0 - W2).
// Round 11: BK=64 phase-1 K-tiles stored as TWO 32-wide panels (same bank
// pattern as BK=32 -> no new conflicts). Occupancy is grid-capped at
// 2 blocks/CU, so the bigger LDS (40 KB) is free; barrier count halves
// (64 -> 32 per phase-1) and in-flight loads + MFMA-per-barrier double.
// Keeps R10's n0-major swizzle (FETCH 42->28 MB verified) and pre-barrier
// fragment hoists.

typedef __attribute__((ext_vector_type(8))) short bf16x8;
typedef __attribute__((ext_vector_type(4))) float f32x4;
typedef __attribute__((ext_vector_type(4))) unsigned short u16x4;

__device__ __forceinline__ float b2f(unsigned short u) {
    union { unsigned int i; float f; } v; v.i = ((unsigned int)u) << 16; return v.f;
}
__device__ __forceinline__ unsigned short f2b(float f) {
    union { float f; unsigned int i; } v; v.f = f;
    unsigned int r = v.i + 0x7FFFu + ((v.i >> 16) & 1u);
    return (unsigned short)(r >> 16);
}

// LDS dest is wave-uniform base + lane*16 (m104/m108 rule).
#define GLOAD_LDS16(g, l) __builtin_amdgcn_global_load_lds( \
    (const __attribute__((address_space(1))) void*)(g),     \
    (__attribute__((address_space(3))) void*)(l), 16, 0, 0)

// ---------------------------------------------------------------------------
// Generic bf16 GEMM (preamble only): C[m,n] = scale * sum_k P[m,k]*QT[n,k].
// ---------------------------------------------------------------------------
__global__ __launch_bounds__(256) void gemm_bt(
    const unsigned short* __restrict__ P, int lda,
    const unsigned short* __restrict__ QT, int ldb,
    unsigned short* __restrict__ C, int ldc,
    int K, float scale)
{
    __shared__ __align__(16) unsigned short As[128 * 32];
    __shared__ __align__(16) unsigned short Bs[128 * 32];
    const int tid = threadIdx.x;
    const int m0 = blockIdx.y << 7, n0 = blockIdx.x << 7;
    const int w = tid >> 6, l = tid & 63;
    const int wm = (w >> 1) << 6, wn = (w & 1) << 6;
    const int lr = l & 15, lq = l >> 4;
    const int arow = tid >> 2, ak = (tid & 3) << 3;
    f32x4 acc[4][4] = {};

    for (int k0 = 0; k0 < K; k0 += 32) {
#pragma unroll
        for (int p = 0; p < 2; ++p)
            GLOAD_LDS16(P + (size_t)(m0 + arow + (p << 6)) * lda + k0 + ak,
                        &As[((arow + (p << 6)) << 5) + ak]);
#pragma unroll
        for (int p = 0; p < 2; ++p)
            GLOAD_LDS16(QT + (size_t)(n0 + arow + (p << 6)) * ldb + k0 + ak,
                        &Bs[((arow + (p << 6)) << 5) + ak]);
        __syncthreads();
        bf16x8 a[4], b[4];
#pragma unroll
        for (int i = 0; i < 4; ++i)
            a[i] = *(const bf16x8*)&As[((wm + (i << 4) + lr) << 5) + (lq << 3)];
#pragma unroll
        for (int j = 0; j < 4; ++j)
            b[j] = *(const bf16x8*)&Bs[((wn + (j << 4) + lr) << 5) + (lq << 3)];
#pragma unroll
        for (int i = 0; i < 4; ++i)
#pragma unroll
            for (int j = 0; j < 4; ++j)
                acc[i][j] = __builtin_amdgcn_mfma_f32_16x16x32_bf16(a[i], b[j], acc[i][j], 0, 0, 0);
        __syncthreads();
    }
#pragma unroll
    for (int i = 0; i < 4; ++i)
#pragma unroll
        for (int j = 0; j < 4; ++j)
#pragma unroll
            for (int r = 0; r < 4; ++r) {
                const int m = m0 + wm + (i << 4) + (lq << 2) + r;
                const int n = n0 + wn + (j << 4) + lr;
                C[(size_t)m * ldc + n] = f2b(acc[i][j][r] * scale);
            }
}

// ---------------------------------------------------------------------------
// cell_gate: grid 512 = (n0-tile major) x (b minor), 256 threads.
// LDS: phase1 staging As(2x 256x32 panels, 32 KB) + Bs(2x 64x32, 8 KB) = 40 KB,
// aliased with [Shs 256x72 | SgoS] (37 KB). Max 40960 B.
// ---------------------------------------------------------------------------
__global__ __launch_bounds__(256) void cell_gate(
    const unsigned short* __restrict__ AA, const unsigned short* __restrict__ XhT,
    const unsigned short* __restrict__ Hb, const unsigned short* __restrict__ WT,
    const float* __restrict__ bias, const float* __restrict__ wx,
    const float* __restrict__ xin, int t,
    const unsigned short* __restrict__ XSgT, int xsrow,
    const unsigned short* __restrict__ Go,
    const float* __restrict__ prW, const float* __restrict__ prb,
    float* __restrict__ Sgo,
    unsigned short* __restrict__ Zb, unsigned short* __restrict__ ZhT,
    unsigned short* __restrict__ R, int dec, int goflag)
{
    __shared__ __align__(16) unsigned char smem[40960];
    unsigned short* As  = (unsigned short*)smem;            // 2 panels x 256x32
    unsigned short* Bs  = (unsigned short*)(smem + 32768);  // 2 panels x 64x32
    unsigned short* Shs = (unsigned short*)smem;            // 256*72 = 36 KB
    float* SgoS = (float*)(smem + 36864);                   // 256 floats
    const int tid = threadIdx.x;
    // n0-major: 64 consecutive blocks share the same AA slice (XCD L2 locality)
    const int b = blockIdx.x & 63, n0 = (blockIdx.x >> 6) << 7;
    const int w = tid >> 6, l = tid & 63;
    const int lr = l & 15, lq = l >> 4;
    const int arow = tid >> 2, ak = (tid & 3) << 3;

    // ---- Phase 1: Sh[256][64] = AA[{n0..n0+127, 1024+n0..}] @ XhT[b-rows]^T
    {
        const int wm = w << 6;   // wave M base: 0,64,128,192
        f32x4 acc[4][4] = {};
        for (int k0 = 0; k0 < 1024; k0 += 64) {
#pragma unroll
            for (int q = 0; q < 2; ++q) {
#pragma unroll
                for (int p = 0; p < 4; ++p) {
                    const int row = arow + (p << 6);
                    const int grow = (p < 2) ? (n0 + row) : (896 + n0 + row);
                    GLOAD_LDS16(AA + (size_t)grow * 1024 + k0 + (q << 5) + ak,
                                &As[(q << 13) + (row << 5) + ak]);
                }
                GLOAD_LDS16(XhT + (size_t)((b << 6) + arow) * 1024 + k0 + (q << 5) + ak,
                            &Bs[(q << 11) + (arow << 5) + ak]);
            }
            __syncthreads();
#pragma unroll
            for (int kc = 0; kc < 2; ++kc) {
                bf16x8 a[4], bb[4];
#pragma unroll
                for (int i = 0; i < 4; ++i)
                    a[i] = *(const bf16x8*)&As[(kc << 13) + ((wm + (i << 4) + lr) << 5) + (lq << 3)];
#pragma unroll
                for (int j = 0; j < 4; ++j)
                    bb[j] = *(const bf16x8*)&Bs[(kc << 11) + (((j << 4) + lr) << 5) + (lq << 3)];
#pragma unroll
                for (int i = 0; i < 4; ++i)
#pragma unroll
                    for (int j = 0; j < 4; ++j)
                        acc[i][j] = __builtin_amdgcn_mfma_f32_16x16x32_bf16(a[i], bb[j], acc[i][j], 0, 0, 0);
            }
            __syncthreads();   // all LDS reads done before next stage / aliasing
        }
        // Sh -> LDS (bf16), overwriting the staging region (lifetimes disjoint)
#pragma unroll
        for (int i = 0; i < 4; ++i)
#pragma unroll
            for (int j = 0; j < 4; ++j)
#pragma unroll
                for (int r = 0; r < 4; ++r) {
                    const int m = wm + (i << 4) + (lq << 2) + r;
                    const int c = (j << 4) + lr;
                    Shs[m * 72 + c] = f2b(acc[i][j][r]);
                }
        if (dec) {
            float pw[4];
#pragma unroll
            for (int j = 0; j < 4; ++j) pw[j] = prW[(j << 4) + lr];
            const float pb0 = prb[0];
#pragma unroll
            for (int i = 0; i < 4; ++i)
#pragma unroll
                for (int r = 0; r < 4; ++r) {
                    float v = acc[i][0][r] * pw[0] + acc[i][1][r] * pw[1]
                            + acc[i][2][r] * pw[2] + acc[i][3][r] * pw[3];
                    v += __shfl_down(v, 8, 16);
                    v += __shfl_down(v, 4, 16);
                    v += __shfl_down(v, 2, 16);
                    v += __shfl_down(v, 1, 16);
                    if (lr == 0) {
                        const int m = wm + (i << 4) + (lq << 2) + r;
                        const int grow = (m < 128) ? (n0 + m) : (896 + n0 + m);
                        // t=0: GO token is zero -> A@go = 0 (goflag==0)
                        const float val = goflag
                            ? (v + pb0 * ((m < 128) ? 1.f : 2.f)) : 0.f;
                        Sgo[(size_t)grow * 64 + b] = val;
                        SgoS[m] = val;
                    }
                }
        }
    }

    // Hoist phase-2 Hb fragments (independent of Shs) above the publish barrier.
    const int wm2 = (w >> 1) << 6, wn2 = (w & 1) << 6;
    bf16x8 hfa[2][4];
#pragma unroll
    for (int kq = 0; kq < 2; ++kq)
#pragma unroll
        for (int i = 0; i < 4; ++i)
            hfa[kq][i] = *(const bf16x8*)(Hb + ((size_t)(b << 10) + n0 + wm2 + (i << 4) + lr) * 64 + (kq << 5) + (lq << 3));

    __syncthreads();   // Shs/SgoS ready for all waves

    // ---- Phase 2: zr = sigmoid([h | Sh_A | Sh_2A2] @ W + bias + corr) ----
    f32x4 acc2[4][4] = {};
    for (int kk0 = 0; kk0 < 192; kk0 += 32) {
        bf16x8 a[4], bb[4];
        if (kk0 < 64) {
#pragma unroll
            for (int i = 0; i < 4; ++i)
                a[i] = hfa[kk0 >> 5][i];
        } else {
            const int rowb = (kk0 >= 128) ? 128 : 0;
            const int c0 = kk0 & 63;
#pragma unroll
            for (int i = 0; i < 4; ++i)
                a[i] = *(const bf16x8*)&Shs[(rowb + wm2 + (i << 4) + lr) * 72 + c0 + (lq << 3)];
        }
#pragma unroll
        for (int j = 0; j < 4; ++j)
            bb[j] = *(const bf16x8*)(WT + (size_t)(wn2 + (j << 4) + lr) * 192 + kk0 + (lq << 3));
#pragma unroll
        for (int i = 0; i < 4; ++i)
#pragma unroll
            for (int j = 0; j < 4; ++j)
                acc2[i][j] = __builtin_amdgcn_mfma_f32_16x16x32_bf16(a[i], bb[j], acc2[i][j], 0, 0, 0);
    }

#pragma unroll
    for (int i = 0; i < 4; ++i) {
        const int nb_loc = wm2 + (i << 4) + (lq << 2);      // local node 0..127
        const int node_base = n0 + nb_loc;
        float c0[4], c1[4], c2[4], c3[4], c4[4], c5[4];
        for (int r = 0; r < 4; ++r) {
            const int node = node_base + r;
            if (!dec) {
                c0[r] = xin[((b * 12 + t) << 10) + node];
                c1[r] = b2f(XSgT[(size_t)(xsrow + t * 64 + b) * 2048 + node]);
                c2[r] = b2f(XSgT[(size_t)(xsrow + t * 64 + b) * 2048 + 1024 + node]);
                c3[r] = c4[r] = c5[r] = 0.f;
            } else {
                c0[r] = b2f(Go[(b << 10) + node]);
                c1[r] = xin[((b * 12 + t) << 10) + node];
                c2[r] = SgoS[nb_loc + r];
                c3[r] = b2f(XSgT[(size_t)(xsrow + t * 64 + b) * 2048 + node]);
                c4[r] = SgoS[128 + nb_loc + r];
                c5[r] = b2f(XSgT[(size_t)(xsrow + t * 64 + b) * 2048 + 1024 + node]);
            }
        }
#pragma unroll
        for (int j = 0; j < 4; ++j) {
            const int jc = wn2 + (j << 4) + lr;
            const float bj = bias[jc];
            const float w0 = wx[jc], w1 = wx[128 + jc], w2 = wx[256 + jc];
            float w3 = 0.f, w4 = 0.f, w5 = 0.f;
            if (dec) { w3 = wx[384 + jc]; w4 = wx[512 + jc]; w5 = wx[640 + jc]; }
            if (jc < 64) {
                u16x4 pack;
                for (int r = 0; r < 4; ++r) {
                    float v = acc2[i][j][r] + bj + c0[r] * w0 + c1[r] * w1 + c2[r] * w2
                              + c3[r] * w3 + c4[r] * w4 + c5[r] * w5;
                    float g = 1.f / (1.f + __expf(-v));
                    const int node = node_base + r;
                    const size_t idx = ((size_t)(b << 10) + node) * 64 + jc;
                    float zh = g * b2f(Hb[idx]);
                    unsigned short zb = f2b(zh);
                    Zb[idx] = zb;
                    pack[r] = zb;
                }
                *(u16x4*)&ZhT[(size_t)((b << 6) + jc) * 1024 + node_base] = pack;
            } else {
                for (int r = 0; r < 4; ++r) {
                    float v = acc2[i][j][r] + bj + c0[r] * w0 + c1[r] * w1 + c2[r] * w2
                              + c3[r] * w3 + c4[r] * w4 + c5[r] * w5;
                    float g = 1.f / (1.f + __expf(-v));
                    const int node = node_base + r;
                    R[((size_t)(b << 10) + node) * 64 + (jc - 64)] = f2b(g);
                }
            }
        }
    }
}

// ---------------------------------------------------------------------------
// cell_update: grid 512 = (n0-tile major) x (b minor), 256 threads.
// ---------------------------------------------------------------------------
__global__ __launch_bounds__(256) void cell_update(
    const unsigned short* __restrict__ AA, const unsigned short* __restrict__ ZhT,
    const unsigned short* __restrict__ Zb, const unsigned short* __restrict__ WT,
    const float* __restrict__ bias, const float* __restrict__ wx,
    const float* __restrict__ xin, int t,
    const unsigned short* __restrict__ XSgT, int xsrow,
    const float* __restrict__ Sgo, const unsigned short* __restrict__ Rg,
    unsigned short* __restrict__ Hb, unsigned short* __restrict__ XhT,
    const float* __restrict__ prW, const float* __restrict__ prb,
    unsigned short* __restrict__ Go, float* __restrict__ outp, int dec)
{
    __shared__ __align__(16) unsigned char smem[40960];
    unsigned short* As  = (unsigned short*)smem;            // 2 panels x 256x32
    unsigned short* Bs  = (unsigned short*)(smem + 32768);  // 2 panels x 64x32
    unsigned short* Shs = (unsigned short*)smem;            // 256*72
    const int tid = threadIdx.x;
    const int b = blockIdx.x & 63, n0 = (blockIdx.x >> 6) << 7;
    const int w = tid >> 6, l = tid & 63;
    const int lr = l & 15, lq = l >> 4;
    const int arow = tid >> 2, ak = (tid & 3) << 3;

    // ---- Phase 1: Sz[256][64] = AA @ ZhT[b-rows]^T ----
    {
        const int wm = w << 6;
        f32x4 acc[4][4] = {};
        for (int k0 = 0; k0 < 1024; k0 += 64) {
#pragma unroll
            for (int q = 0; q < 2; ++q) {
#pragma unroll
                for (int p = 0; p < 4; ++p) {
                    const int row = arow + (p << 6);
                    const int grow = (p < 2) ? (n0 + row) : (896 + n0 + row);
                    GLOAD_LDS16(AA + (size_t)grow * 1024 + k0 + (q << 5) + ak,
                                &As[(q << 13) + (row << 5) + ak]);
                }
                GLOAD_LDS16(ZhT + (size_t)((b << 6) + arow) * 1024 + k0 + (q << 5) + ak,
                            &Bs[(q << 11) + (arow << 5) + ak]);
            }
            __syncthreads();
#pragma unroll
            for (int kc = 0; kc < 2; ++kc) {
                bf16x8 a[4], bb[4];
#pragma unroll
                for (int i = 0; i < 4; ++i)
                    a[i] = *(const bf16x8*)&As[(kc << 13) + ((wm + (i << 4) + lr) << 5) + (lq << 3)];
#pragma unroll
                for (int j = 0; j < 4; ++j)
                    bb[j] = *(const bf16x8*)&Bs[(kc << 11) + (((j << 4) + lr) << 5) + (lq << 3)];
#pragma unroll
                for (int i = 0; i < 4; ++i)
#pragma unroll
                    for (int j = 0; j < 4; ++j)
                        acc[i][j] = __builtin_amdgcn_mfma_f32_16x16x32_bf16(a[i], bb[j], acc[i][j], 0, 0, 0);
            }
            __syncthreads();
        }
#pragma unroll
        for (int i = 0; i < 4; ++i)
#pragma unroll
            for (int j = 0; j < 4; ++j)
#pragma unroll
                for (int r = 0; r < 4; ++r) {
                    const int m = wm + (i << 4) + (lq << 2) + r;
                    const int c = (j << 4) + lr;
                    Shs[m * 72 + c] = f2b(acc[i][j][r]);
                }
    }

    // Hoist phase-2 Zb fragments above the publish barrier.
    const int wm2 = w << 5;
    bf16x8 zfa[2][2];
#pragma unroll
    for (int kq = 0; kq < 2; ++kq)
#pragma unroll
        for (int i = 0; i < 2; ++i)
            zfa[kq][i] = *(const bf16x8*)(Zb + ((size_t)(b << 10) + n0 + wm2 + (i << 4) + lr) * 64 + (kq << 5) + (lq << 3));

    __syncthreads();

    // ---- Phase 2: hc = tanh([zh | Sz_A | Sz_2A2] @ Wu + bias + corr) ----
    f32x4 acc2[2][4] = {};
    for (int kk0 = 0; kk0 < 192; kk0 += 32) {
        bf16x8 a[2], bb[4];
        if (kk0 < 64) {
#pragma unroll
            for (int i = 0; i < 2; ++i)
                a[i] = zfa[kk0 >> 5][i];
        } else {
            const int rowb = (kk0 >= 128) ? 128 : 0;
            const int c0 = kk0 & 63;
#pragma unroll
            for (int i = 0; i < 2; ++i)
                a[i] = *(const bf16x8*)&Shs[(rowb + wm2 + (i << 4) + lr) * 72 + c0 + (lq << 3)];
        }
#pragma unroll
        for (int j = 0; j < 4; ++j)
            bb[j] = *(const bf16x8*)(WT + (size_t)((j << 4) + lr) * 192 + kk0 + (lq << 3));
#pragma unroll
        for (int i = 0; i < 2; ++i)
#pragma unroll
            for (int j = 0; j < 4; ++j)
                acc2[i][j] = __builtin_amdgcn_mfma_f32_16x16x32_bf16(a[i], bb[j], acc2[i][j], 0, 0, 0);
    }

    float pw[4];
    if (dec) {
#pragma unroll
        for (int j = 0; j < 4; ++j) pw[j] = prW[(j << 4) + lr];
    }

#pragma unroll
    for (int i = 0; i < 2; ++i) {
        const int node_base = n0 + wm2 + (i << 4) + (lq << 2);
        float c0[4], c1[4], c2[4], c3[4], c4[4], c5[4];
        for (int r = 0; r < 4; ++r) {
            const int node = node_base + r;
            if (!dec) {
                c0[r] = xin[((b * 12 + t) << 10) + node];
                c1[r] = b2f(XSgT[(size_t)(xsrow + t * 64 + b) * 2048 + node]);
                c2[r] = b2f(XSgT[(size_t)(xsrow + t * 64 + b) * 2048 + 1024 + node]);
                c3[r] = c4[r] = c5[r] = 0.f;
            } else {
                c0[r] = b2f(Go[(b << 10) + node]);
                c1[r] = xin[((b * 12 + t) << 10) + node];
                c2[r] = Sgo[(size_t)node * 64 + b];
                c3[r] = b2f(XSgT[(size_t)(xsrow + t * 64 + b) * 2048 + node]);
                c4[r] = Sgo[(size_t)(1024 + node) * 64 + b];
                c5[r] = b2f(XSgT[(size_t)(xsrow + t * 64 + b) * 2048 + 1024 + node]);
            }
        }
        float psum[4] = {0.f, 0.f, 0.f, 0.f};
#pragma unroll
        for (int j = 0; j < 4; ++j) {
            const int jc = (j << 4) + lr;
            const float bj = bias[jc];
            const float w0 = wx[jc], w1 = wx[64 + jc], w2 = wx[128 + jc];
            float w3 = 0.f, w4 = 0.f, w5 = 0.f;
            if (dec) { w3 = wx[192 + jc]; w4 = wx[256 + jc]; w5 = wx[320 + jc]; }
            u16x4 pack;
            for (int r = 0; r < 4; ++r) {
                float v = acc2[i][j][r] + bj + c0[r] * w0 + c1[r] * w1 + c2[r] * w2
                          + c3[r] * w3 + c4[r] * w4 + c5[r] * w5;
                float hc = tanhf(v);
                const int node = node_base + r;
                const size_t idx = ((size_t)(b << 10) + node) * 64 + jc;
                float rr = b2f(Rg[idx]);
                float hn = rr * b2f(Hb[idx]) + (1.f - rr) * hc;
                unsigned short hb = f2b(hn);
                Hb[idx] = hb;
                pack[r] = hb;
                if (dec) psum[r] += hn * pw[j];
            }
            *(u16x4*)&XhT[(size_t)((b << 6) + jc) * 1024 + node_base] = pack;
        }
        if (dec) {
#pragma unroll
            for (int r = 0; r < 4; ++r) {
                float v = psum[r];
                v += __shfl_down(v, 8, 16);
                v += __shfl_down(v, 4, 16);
                v += __shfl_down(v, 2, 16);
                v += __shfl_down(v, 1, 16);
                if (lr == 0) {
                    const int node = node_base + r;
                    const float go = v + prb[0];
                    Go[(b << 10) + node] = f2b(go);
                    outp[((size_t)(b * 12 + t) << 10) + node] = go;
                }
            }
        }
    }
}

// ---------------------------------------------------------------------------
__global__ __launch_bounds__(256) void adj_softmax(
    const float* __restrict__ E, unsigned short* __restrict__ A)
{
    __shared__ float Es[8192];
    __shared__ float vals[1024];
    __shared__ float red[8];
    const int tid = threadIdx.x;
    const int r = blockIdx.x;
    for (int i = tid; i < 8192; i += 256) Es[i] = E[i];
    __syncthreads();
    float er[8];
#pragma unroll
    for (int e = 0; e < 8; ++e) er[e] = Es[(r << 3) + e];
    float lmax = -1e30f;
    for (int c = tid; c < 1024; c += 256) {
        float s = 0.f;
#pragma unroll
        for (int e = 0; e < 8; ++e) s += er[e] * Es[(c << 3) + e];
        s = fmaxf(s, 0.f);
        vals[c] = s;
        lmax = fmaxf(lmax, s);
    }
    for (int off = 32; off; off >>= 1) lmax = fmaxf(lmax, __shfl_down(lmax, off, 64));
    if ((tid & 63) == 0) red[tid >> 6] = lmax;
    __syncthreads();
    const float m = fmaxf(fmaxf(red[0], red[1]), fmaxf(red[2], red[3]));
    float lsum = 0.f;
    for (int c = tid; c < 1024; c += 256) {
        float e = __expf(vals[c] - m);
        vals[c] = e;
        lsum += e;
    }
    for (int off = 32; off; off >>= 1) lsum += __shfl_down(lsum, off, 64);
    if ((tid & 63) == 0) red[4 + (tid >> 6)] = lsum;
    __syncthreads();
    const float inv = 1.f / (red[4] + red[5] + red[6] + red[7]);
    for (int c = tid; c < 1024; c += 256)
        A[(r << 10) + c] = f2b(vals[c] * inv);
}

__global__ __launch_bounds__(256) void transpose_bf16(
    const unsigned short* __restrict__ src, unsigned short* __restrict__ dst)
{
    __shared__ unsigned short tile[64][65];
    const int bx = blockIdx.x & 15, by = blockIdx.x >> 4;
    const int x0 = bx << 6, y0 = by << 6;
    for (int i = threadIdx.x; i < 4096; i += 256) {
        const int r = i >> 6, c = i & 63;
        tile[r][c] = src[((y0 + r) << 10) + x0 + c];
    }
    __syncthreads();
    for (int i = threadIdx.x; i < 4096; i += 256) {
        const int r = i >> 6, c = i & 63;
        dst[((x0 + r) << 10) + y0 + c] = tile[c][r];
    }
}

__global__ __launch_bounds__(256) void build_xall(
    const float* __restrict__ x, const float* __restrict__ y,
    unsigned short* __restrict__ XallT)
{
    const int id = blockIdx.x * 256 + threadIdx.x;
    const int row = id >> 10, n = id & 1023;
    int t, b;
    const float* src;
    if (row < 768) { t = row >> 6; b = row & 63; src = x; }
    else { const int rr = row - 768; t = rr >> 6; b = rr & 63; src = y; }
    XallT[id] = f2b(src[((b * 12 + t) << 10) + n]);
}

__global__ __launch_bounds__(256) void wprep(
    const float* egW, const float* egb,
    const float* euW, const float* eub,
    const float* dgW, const float* dgb,
    const float* duW, const float* dub,
    const float* pW, const float* pb,
    unsigned short* WgTe, unsigned short* WuTe, unsigned short* WgTd, unsigned short* WuTd,
    float* wxge, float* wxue, float* wxgd, float* wxud,
    float* bge, float* bue, float* bgd, float* bud,
    float* projW, float* projb)
{
    const int tid0 = blockIdx.x * 256 + threadIdx.x;
    const int stride = 256 * gridDim.x;
    for (int i = tid0; i < 128 * 192; i += stride) {
        const int j = i / 192, kk = i % 192, k = kk >> 6, c = kk & 63;
        float v = egW[(k * 65 + 1 + c) * 128 + j];
        if (k == 0) v -= egW[(131 + c) * 128 + j];
        WgTe[i] = f2b(v);
    }
    for (int i = tid0; i < 64 * 192; i += stride) {
        const int j = i / 192, kk = i % 192, k = kk >> 6, c = kk & 63;
        float v = euW[(k * 65 + 1 + c) * 64 + j];
        if (k == 0) v -= euW[(131 + c) * 64 + j];
        WuTe[i] = f2b(v);
    }
    for (int i = tid0; i < 128 * 192; i += stride) {
        const int j = i / 192, kk = i % 192, k = kk >> 6, c = kk & 63;
        float v = dgW[(k * 66 + 2 + c) * 128 + j];
        if (k == 0) v -= dgW[(134 + c) * 128 + j];
        WgTd[i] = f2b(v);
    }
    for (int i = tid0; i < 64 * 192; i += stride) {
        const int j = i / 192, kk = i % 192, k = kk >> 6, c = kk & 63;
        float v = duW[(k * 66 + 2 + c) * 64 + j];
        if (k == 0) v -= duW[(134 + c) * 64 + j];
        WuTd[i] = f2b(v);
    }
    for (int i = tid0; i < 384; i += stride) {
        const int k = i >> 7, j = i & 127;
        float v;
        if (k == 0) v = egW[j] - egW[130 * 128 + j];
        else if (k == 1) v = egW[65 * 128 + j];
        else v = egW[130 * 128 + j];
        wxge[i] = v;
    }
    for (int i = tid0; i < 192; i += stride) {
        const int k = i >> 6, j = i & 63;
        float v;
        if (k == 0) v = euW[j] - euW[130 * 64 + j];
        else if (k == 1) v = euW[65 * 64 + j];
        else v = euW[130 * 64 + j];
        wxue[i] = v;
    }
    for (int i = tid0; i < 768; i += stride) {
        const int k = i >> 7, j = i & 127;
        float v;
        switch (k) {
            case 0: v = dgW[j] - dgW[132 * 128 + j]; break;
            case 1: v = dgW[128 + j] - dgW[133 * 128 + j]; break;
            case 2: v = dgW[66 * 128 + j]; break;
            case 3: v = dgW[67 * 128 + j]; break;
            case 4: v = dgW[132 * 128 + j]; break;
            default: v = dgW[133 * 128 + j]; break;
        }
        wxgd[i] = v;
    }
    for (int i = tid0; i < 384; i += stride) {
        const int k = i >> 6, j = i & 63;
        float v;
        switch (k) {
            case 0: v = duW[j] - duW[132 * 64 + j]; break;
            case 1: v = duW[64 + j] - duW[133 * 64 + j]; break;
            case 2: v = duW[66 * 64 + j]; break;
            case 3: v = duW[67 * 64 + j]; break;
            case 4: v = duW[132 * 64 + j]; break;
            default: v = duW[133 * 64 + j]; break;
        }
        wxud[i] = v;
    }
    for (int i = tid0; i < 128; i += stride) bge[i] = egb[i];
    for (int i = tid0; i < 64; i += stride) bue[i] = eub[i];
    for (int i = tid0; i < 128; i += stride) bgd[i] = dgb[i];
    for (int i = tid0; i < 64; i += stride) bud[i] = dub[i];
    for (int i = tid0; i < 64; i += stride) projW[i] = pW[i];
    if (tid0 == 0) projb[0] = pb[0];
}

// ---------------------------------------------------------------------------
extern "C" void kernel_launch(void* const* d_in, const int* in_sizes, int n_in,
                              void* d_out, int out_size, void* d_ws, size_t ws_size,
                              hipStream_t stream)
{
    (void)in_sizes; (void)n_in; (void)out_size; (void)ws_size;
    const float* x    = (const float*)d_in[0];
    const float* ycov = (const float*)d_in[1];
    const float* E    = (const float*)d_in[2];
    const float* egW  = (const float*)d_in[3];
    const float* egb  = (const float*)d_in[4];
    const float* euW  = (const float*)d_in[5];
    const float* eub  = (const float*)d_in[6];
    const float* dgW  = (const float*)d_in[7];
    const float* dgb  = (const float*)d_in[8];
    const float* duW  = (const float*)d_in[9];
    const float* dub  = (const float*)d_in[10];
    const float* pW   = (const float*)d_in[11];
    const float* pb   = (const float*)d_in[12];
    float* out = (float*)d_out;

    size_t off = 0;
    auto carve = [&](size_t bytes) -> void* {
        void* p = (char*)d_ws + off;
        off += (bytes + 255) & ~(size_t)255;
        return p;
    };
    unsigned short* AA    = (unsigned short*)carve(2048ull * 1024 * 2); // [A; 2A^2]
    unsigned short* XSgT  = (unsigned short*)carve(1536ull * 2048 * 2);
    unsigned short* XhT   = (unsigned short*)carve(4096ull * 1024 * 2);
    unsigned short* ZhT   = (unsigned short*)carve(4096ull * 1024 * 2);
    unsigned short* Hb    = (unsigned short*)carve(65536ull * 64 * 2);
    unsigned short* Zb    = (unsigned short*)carve(65536ull * 64 * 2);
    unsigned short* R     = (unsigned short*)carve(65536ull * 64 * 2);
    float*          Sgo   = (float*)carve(2048ull * 64 * 4);
    unsigned short* Go    = (unsigned short*)carve(65536ull * 2);
    unsigned short* WgTe  = (unsigned short*)carve(128ull * 192 * 2);
    unsigned short* WuTe  = (unsigned short*)carve(64ull * 192 * 2);
    unsigned short* WgTd  = (unsigned short*)carve(128ull * 192 * 2);
    unsigned short* WuTd  = (unsigned short*)carve(64ull * 192 * 2);
    float* wxge = (float*)carve(384 * 4);
    float* wxue = (float*)carve(192 * 4);
    float* wxgd = (float*)carve(768 * 4);
    float* wxud = (float*)carve(384 * 4);
    float* bge  = (float*)carve(128 * 4);
    float* bue  = (float*)carve(64 * 4);
    float* bgd  = (float*)carve(128 * 4);
    float* bud  = (float*)carve(64 * 4);
    float* prW  = (float*)carve(64 * 4);
    float* prb  = (float*)carve(4);
    // Aliases: AT and XallT live inside Zb (both consumed before Zb's first write).
    unsigned short* AT    = Zb;
    unsigned short* XallT = Zb + 1024ull * 1024;

    hipMemsetAsync(XhT, 0, 4096ull * 1024 * 2, stream);
    hipMemsetAsync(Hb, 0, 65536ull * 64 * 2, stream);
    hipMemsetAsync(Go, 0, 65536ull * 2, stream);

    adj_softmax<<<1024, 256, 0, stream>>>(E, AA);
    transpose_bf16<<<256, 256, 0, stream>>>(AA, AT);
    gemm_bt<<<dim3(8, 8), 256, 0, stream>>>(AA, 1024, AT, 1024, AA + 1024 * 1024, 1024, 1024, 2.0f);
    build_xall<<<6144, 256, 0, stream>>>(x, ycov, XallT);
    gemm_bt<<<dim3(16, 12), 256, 0, stream>>>(XallT, 1024, AA, 1024, XSgT, 2048, 1024, 1.0f);
    wprep<<<64, 256, 0, stream>>>(egW, egb, euW, eub, dgW, dgb, duW, dub, pW, pb,
                                  WgTe, WuTe, WgTd, WuTd, wxge, wxue, wxgd, wxud,
                                  bge, bue, bgd, bud, prW, prb);

    for (int t = 0; t < 12; ++t) {  // encoder
        cell_gate<<<512, 256, 0, stream>>>(AA, XhT, Hb, WgTe, bge, wxge, x, t, XSgT, 0,
                                           Go, prW, prb, Sgo, Zb, ZhT, R, 0, 0);
        cell_update<<<512, 256, 0, stream>>>(AA, ZhT, Zb, WuTe, bue, wxue, x, t, XSgT, 0,
                                             Sgo, R, Hb, XhT, prW, prb, Go, out, 0);
    }
    for (int t = 0; t < 12; ++t) {  // decoder
        cell_gate<<<512, 256, 0, stream>>>(AA, XhT, Hb, WgTd, bgd, wxgd, ycov, t, XSgT, 768,
                                           Go, prW, prb, Sgo, Zb, ZhT, R, 1, t > 0 ? 1 : 0);
        cell_update<<<512, 256, 0, stream>>>(AA, ZhT, Zb, WuTd, bud, wxud, ycov, t, XSgT, 768,
                                             Sgo, R, Hb, XhT, prW, prb, Go, out, 1);
    }
}